// Round 1
// baseline (2054.463 us; speedup 1.0000x reference)
//
#include <hip/hip_runtime.h>
#include <hip/hip_bf16.h>

#define NN 100000
#define EE 1600000
#define IN_DIM 512
#define HID 64

// ---------------- degree / dis ----------------
__global__ void deg_kernel(const int* __restrict__ dst, float* __restrict__ deg) {
    int e = blockIdx.x * 256 + threadIdx.x;
    if (e < EE) atomicAdd(&deg[dst[e]], 1.0f);
}

__global__ void dis_kernel(float* __restrict__ deg) {
    int i = blockIdx.x * 256 + threadIdx.x;
    if (i < NN) deg[i] = rsqrtf(deg[i] + 1.0f);  // +1 self-loop; deg>=1 always
}

// ---------------- GEMM1: xt1 = x @ W1  [N,512]x[512,64] ----------------
// block = 256 threads = 4 rows x 64 cols. N % 4 == 0.
__global__ void gemm1_kernel(const float* __restrict__ x,
                             const float* __restrict__ W1,
                             float* __restrict__ xt1) {
    __shared__ float xs[4][IN_DIM];
    const int tid = threadIdx.x;
    const int row0 = blockIdx.x * 4;
    // stage 4 rows of x (4*512 floats = 512 float4)
    const float4* xv = (const float4*)(x + (size_t)row0 * IN_DIM);
    float4* xsv = (float4*)&xs[0][0];
    xsv[tid] = xv[tid];
    xsv[tid + 256] = xv[tid + 256];
    __syncthreads();

    const int r = tid >> 6;   // wave-uniform: each wave owns one row
    const int c = tid & 63;
    const float* xr = xs[r];
    float acc = 0.f;
#pragma unroll 8
    for (int k = 0; k < IN_DIM; ++k) {
        acc += xr[k] * W1[k * HID + c];   // coalesced 256B per wave, L1-resident W1
    }
    xt1[(size_t)(row0 + r) * HID + c] = acc;
}

// ---------------- aggregation layer1: agg1[dst] += xt1[src]*norm ----------------
// 16 threads per edge, 4 feats each (float4 gather + 4 atomics)
__global__ void agg1_kernel(const int* __restrict__ src, const int* __restrict__ dst,
                            const float* __restrict__ dis,
                            const float* __restrict__ xt1,
                            float* __restrict__ agg1) {
    int t = blockIdx.x * 256 + threadIdx.x;
    int e = t >> 4;
    if (e >= EE) return;
    int g = t & 15;
    int s = src[e], d = dst[e];
    float nrm = dis[s] * dis[d];
    float4 v = ((const float4*)(xt1 + (size_t)s * HID))[g];
    float* outp = agg1 + (size_t)d * HID + g * 4;
    atomicAdd(outp + 0, v.x * nrm);
    atomicAdd(outp + 1, v.y * nrm);
    atomicAdd(outp + 2, v.z * nrm);
    atomicAdd(outp + 3, v.w * nrm);
}

// ---------------- epilogue1: h1 = relu(agg1 + xt1*dis^2 + b1), in-place into xt1 ----
__global__ void epilogue1_kernel(float* __restrict__ xt1,
                                 const float* __restrict__ agg1,
                                 const float* __restrict__ dis,
                                 const float* __restrict__ b1) {
    size_t idx = (size_t)blockIdx.x * 256 + threadIdx.x;
    if (idx >= (size_t)NN * HID) return;
    int i = idx >> 6;
    int c = idx & 63;
    float d = dis[i];
    float v = agg1[idx] + xt1[idx] * d * d + b1[c];
    xt1[idx] = fmaxf(v, 0.f);
}

// ---------------- GEMM2: xt2 = h1 @ W2  [N,64]x[64,2] ----------------
__global__ void gemm2_kernel(const float* __restrict__ h1,
                             const float* __restrict__ W2,
                             float* __restrict__ xt2) {
    int i = blockIdx.x * 256 + threadIdx.x;
    if (i >= NN) return;
    const float4* hv = (const float4*)(h1 + (size_t)i * HID);
    float a0 = 0.f, a1 = 0.f;
#pragma unroll
    for (int k4 = 0; k4 < HID / 4; ++k4) {
        float4 h = hv[k4];
        int k = k4 * 4;
        a0 += h.x * W2[(k + 0) * 2 + 0] + h.y * W2[(k + 1) * 2 + 0]
            + h.z * W2[(k + 2) * 2 + 0] + h.w * W2[(k + 3) * 2 + 0];
        a1 += h.x * W2[(k + 0) * 2 + 1] + h.y * W2[(k + 1) * 2 + 1]
            + h.z * W2[(k + 2) * 2 + 1] + h.w * W2[(k + 3) * 2 + 1];
    }
    xt2[(size_t)i * 2 + 0] = a0;
    xt2[(size_t)i * 2 + 1] = a1;
}

// ---------------- aggregation layer2 ----------------
__global__ void agg2_kernel(const int* __restrict__ src, const int* __restrict__ dst,
                            const float* __restrict__ dis,
                            const float* __restrict__ xt2,
                            float* __restrict__ agg2) {
    int e = blockIdx.x * 256 + threadIdx.x;
    if (e >= EE) return;
    int s = src[e], d = dst[e];
    float nrm = dis[s] * dis[d];
    float2 v = *(const float2*)(xt2 + (size_t)s * 2);
    atomicAdd(&agg2[(size_t)d * 2 + 0], v.x * nrm);
    atomicAdd(&agg2[(size_t)d * 2 + 1], v.y * nrm);
}

// ---------------- final: out = log_softmax(agg2 + xt2*dis^2 + b2) ----------------
__global__ void final_kernel(const float* __restrict__ xt2,
                             const float* __restrict__ agg2,
                             const float* __restrict__ dis,
                             const float* __restrict__ b2,
                             float* __restrict__ out) {
    int i = blockIdx.x * 256 + threadIdx.x;
    if (i >= NN) return;
    float d = dis[i];
    float d2 = d * d;
    float v0 = agg2[(size_t)i * 2 + 0] + xt2[(size_t)i * 2 + 0] * d2 + b2[0];
    float v1 = agg2[(size_t)i * 2 + 1] + xt2[(size_t)i * 2 + 1] * d2 + b2[1];
    float m = fmaxf(v0, v1);
    float lse = m + logf(expf(v0 - m) + expf(v1 - m));
    out[(size_t)i * 2 + 0] = v0 - lse;
    out[(size_t)i * 2 + 1] = v1 - lse;
}

extern "C" void kernel_launch(void* const* d_in, const int* in_sizes, int n_in,
                              void* d_out, int out_size, void* d_ws, size_t ws_size,
                              hipStream_t stream) {
    const float* x  = (const float*)d_in[0];
    const int* ei   = (const int*)d_in[1];      // [2,E] int32
    const float* W1 = (const float*)d_in[2];    // [512,64]
    const float* b1 = (const float*)d_in[3];    // [64]
    const float* W2 = (const float*)d_in[4];    // [64,2]
    const float* b2 = (const float*)d_in[5];    // [2]
    const int* src = ei;
    const int* dst = ei + EE;
    float* out = (float*)d_out;

    // workspace layout (floats)
    float* ws   = (float*)d_ws;
    float* xt1  = ws;                                  // N*64  (becomes h1 in-place)
    float* agg1 = ws + (size_t)NN * HID;               // N*64
    float* dis  = ws + (size_t)2 * NN * HID;           // N
    float* xt2  = dis + NN;                            // N*2
    float* agg2 = xt2 + (size_t)NN * 2;                // N*2

    // zero accumulators
    hipMemsetAsync(dis,  0, sizeof(float) * NN, stream);
    hipMemsetAsync(agg1, 0, sizeof(float) * (size_t)NN * HID, stream);
    hipMemsetAsync(agg2, 0, sizeof(float) * (size_t)NN * 2, stream);

    // degree -> dis = rsqrt(deg+1)
    deg_kernel<<<(EE + 255) / 256, 256, 0, stream>>>(dst, dis);
    dis_kernel<<<(NN + 255) / 256, 256, 0, stream>>>(dis);

    // layer 1
    gemm1_kernel<<<NN / 4, 256, 0, stream>>>(x, W1, xt1);
    agg1_kernel<<<(EE * 16 + 255) / 256, 256, 0, stream>>>(src, dst, dis, xt1, agg1);
    epilogue1_kernel<<<((size_t)NN * HID + 255) / 256, 256, 0, stream>>>(xt1, agg1, dis, b1);

    // layer 2
    gemm2_kernel<<<(NN + 255) / 256, 256, 0, stream>>>(xt1, W2, xt2);
    agg2_kernel<<<(EE + 255) / 256, 256, 0, stream>>>(src, dst, dis, xt2, agg2);
    final_kernel<<<(NN + 255) / 256, 256, 0, stream>>>(xt2, agg2, dis, b2, out);
}

// Round 2
// 722.675 us; speedup vs baseline: 2.8429x; 2.8429x over previous
//
#include <hip/hip_runtime.h>
#include <hip/hip_bf16.h>

#define NN 100000
#define EE 1600000
#define IN_DIM 512
#define HID 64
#define SCAN_CHUNK 1024

// ---------------- degree histogram (int) ----------------
__global__ void deg_kernel(const int* __restrict__ dst, int* __restrict__ counts) {
    int e = blockIdx.x * 256 + threadIdx.x;
    if (e < EE) atomicAdd(&counts[dst[e]], 1);
}

__global__ void dis_kernel(const int* __restrict__ counts, float* __restrict__ dis) {
    int i = blockIdx.x * 256 + threadIdx.x;
    if (i < NN) dis[i] = rsqrtf((float)counts[i] + 1.0f);  // +1 self-loop
}

// ---------------- 3-kernel exclusive scan over counts -> offsets ----------------
__global__ void scan1_kernel(const int* __restrict__ counts, int* __restrict__ offsets,
                             int* __restrict__ blocksums) {
    __shared__ int lds[256];
    const int t = threadIdx.x;
    const int base = blockIdx.x * SCAN_CHUNK + t * 4;
    int v[4];
    int s = 0;
#pragma unroll
    for (int k = 0; k < 4; ++k) {
        v[k] = (base + k < NN) ? counts[base + k] : 0;
        s += v[k];
    }
    lds[t] = s;
    __syncthreads();
    for (int off = 1; off < 256; off <<= 1) {
        int add = (t >= off) ? lds[t - off] : 0;
        __syncthreads();
        lds[t] += add;
        __syncthreads();
    }
    int excl = lds[t] - s;
    if (t == 255) blocksums[blockIdx.x] = lds[t];
    int run = excl;
#pragma unroll
    for (int k = 0; k < 4; ++k) {
        if (base + k < NN) offsets[base + k] = run;
        run += v[k];
    }
}

__global__ void scan2_kernel(int* __restrict__ blocksums, int nb) {
    if (threadIdx.x == 0) {
        int run = 0;
        for (int i = 0; i < nb; ++i) { int v = blocksums[i]; blocksums[i] = run; run += v; }
    }
}

__global__ void scan3_kernel(int* __restrict__ offsets, int* __restrict__ cursor,
                             const int* __restrict__ blocksums) {
    int i = blockIdx.x * 256 + threadIdx.x;
    if (i < NN) {
        int v = offsets[i] + blocksums[i >> 10];
        offsets[i] = v;
        cursor[i] = v;
    }
}

// ---------------- scatter edges into CSR (sorted by dst) ----------------
__global__ void scatter_kernel(const int* __restrict__ src, const int* __restrict__ dst,
                               int* __restrict__ cursor, int* __restrict__ sorted_src) {
    int e = blockIdx.x * 256 + threadIdx.x;
    if (e >= EE) return;
    int d = dst[e];
    int pos = atomicAdd(&cursor[d], 1);
    sorted_src[pos] = src[e];
}
// after scatter: cursor[i] == end of segment i, offsets[i] == start

// ---------------- GEMM1: xt1 = x @ W1  [N,512]x[512,64] ----------------
__global__ void gemm1_kernel(const float* __restrict__ x,
                             const float* __restrict__ W1,
                             float* __restrict__ xt1) {
    __shared__ float xs[4][IN_DIM];
    const int tid = threadIdx.x;
    const int row0 = blockIdx.x * 4;
    const float4* xv = (const float4*)(x + (size_t)row0 * IN_DIM);
    float4* xsv = (float4*)&xs[0][0];
    xsv[tid] = xv[tid];
    xsv[tid + 256] = xv[tid + 256];
    __syncthreads();

    const int r = tid >> 6;
    const int c = tid & 63;
    const float* xr = xs[r];
    float acc = 0.f;
#pragma unroll 8
    for (int k = 0; k < IN_DIM; ++k) {
        acc += xr[k] * W1[k * HID + c];
    }
    xt1[(size_t)(row0 + r) * HID + c] = acc;
}

// ---------------- pull aggregation layer1 (wave per node) + fused epilogue ----
__global__ void agg1_csr_kernel(const int* __restrict__ offsets, const int* __restrict__ cursor,
                                const int* __restrict__ sorted_src,
                                const float* __restrict__ dis,
                                const float* __restrict__ xt1,
                                const float* __restrict__ b1,
                                float* __restrict__ h1) {
    int node = blockIdx.x * 4 + (threadIdx.x >> 6);
    if (node >= NN) return;
    int lane = threadIdx.x & 63;
    int beg = offsets[node], end = cursor[node];
    float dd = dis[node];
    float acc = xt1[(size_t)node * HID + lane] * (dd * dd);  // self-loop
    for (int base = beg; base < end; base += 64) {
        int m = min(64, end - base);
        int s = 0;
        float nd = 0.f;
        if (lane < m) {
            s = sorted_src[base + lane];   // coalesced batch load of edge list
            nd = dis[s];
        }
        for (int j = 0; j < m; ++j) {
            int sj = __shfl(s, j);
            float nj = __shfl(nd, j);
            acc += xt1[(size_t)sj * HID + lane] * (nj * dd);  // coalesced 256B row
        }
    }
    h1[(size_t)node * HID + lane] = fmaxf(acc + b1[lane], 0.f);
}

// ---------------- GEMM2: xt2 = h1 @ W2  [N,64]x[64,2] ----------------
__global__ void gemm2_kernel(const float* __restrict__ h1,
                             const float* __restrict__ W2,
                             float* __restrict__ xt2) {
    int i = blockIdx.x * 256 + threadIdx.x;
    if (i >= NN) return;
    const float4* hv = (const float4*)(h1 + (size_t)i * HID);
    float a0 = 0.f, a1 = 0.f;
#pragma unroll
    for (int k4 = 0; k4 < HID / 4; ++k4) {
        float4 h = hv[k4];
        int k = k4 * 4;
        a0 += h.x * W2[(k + 0) * 2 + 0] + h.y * W2[(k + 1) * 2 + 0]
            + h.z * W2[(k + 2) * 2 + 0] + h.w * W2[(k + 3) * 2 + 0];
        a1 += h.x * W2[(k + 0) * 2 + 1] + h.y * W2[(k + 1) * 2 + 1]
            + h.z * W2[(k + 2) * 2 + 1] + h.w * W2[(k + 3) * 2 + 1];
    }
    xt2[(size_t)i * 2 + 0] = a0;
    xt2[(size_t)i * 2 + 1] = a1;
}

// ---------------- pull aggregation layer2 + log_softmax (thread per node) ----
__global__ void agg2_final_kernel(const int* __restrict__ offsets, const int* __restrict__ cursor,
                                  const int* __restrict__ sorted_src,
                                  const float* __restrict__ dis,
                                  const float* __restrict__ xt2,
                                  const float* __restrict__ b2,
                                  float* __restrict__ out) {
    int node = blockIdx.x * 256 + threadIdx.x;
    if (node >= NN) return;
    int beg = offsets[node], end = cursor[node];
    float dd = dis[node];
    float d2 = dd * dd;
    float a0 = xt2[(size_t)node * 2 + 0] * d2;
    float a1 = xt2[(size_t)node * 2 + 1] * d2;
    for (int p = beg; p < end; ++p) {
        int s = sorted_src[p];
        float nrm = dis[s] * dd;
        float2 v = *(const float2*)(xt2 + (size_t)s * 2);
        a0 += v.x * nrm;
        a1 += v.y * nrm;
    }
    float v0 = a0 + b2[0], v1 = a1 + b2[1];
    float m = fmaxf(v0, v1);
    float lse = m + logf(expf(v0 - m) + expf(v1 - m));
    out[(size_t)node * 2 + 0] = v0 - lse;
    out[(size_t)node * 2 + 1] = v1 - lse;
}

extern "C" void kernel_launch(void* const* d_in, const int* in_sizes, int n_in,
                              void* d_out, int out_size, void* d_ws, size_t ws_size,
                              hipStream_t stream) {
    const float* x  = (const float*)d_in[0];
    const int* ei   = (const int*)d_in[1];
    const float* W1 = (const float*)d_in[2];
    const float* b1 = (const float*)d_in[3];
    const float* W2 = (const float*)d_in[4];
    const float* b2 = (const float*)d_in[5];
    const int* src = ei;
    const int* dst = ei + EE;
    float* out = (float*)d_out;

    // workspace layout
    float* ws         = (float*)d_ws;
    float* xt1        = ws;                                   // N*64
    float* h1         = xt1 + (size_t)NN * HID;               // N*64
    float* dis        = h1 + (size_t)NN * HID;                // N
    int*   counts     = (int*)(dis + NN);                     // N
    int*   offsets    = counts + NN;                          // N
    int*   cursor     = offsets + NN;                         // N
    int*   blocksums  = cursor + NN;                          // 128
    int*   sorted_src = blocksums + 128;                      // E
    float* xt2        = (float*)(sorted_src + EE);            // N*2

    const int NB = (NN + SCAN_CHUNK - 1) / SCAN_CHUNK;        // 98

    hipMemsetAsync(counts, 0, sizeof(int) * NN, stream);

    // degree + normalization
    deg_kernel<<<(EE + 255) / 256, 256, 0, stream>>>(dst, counts);
    dis_kernel<<<(NN + 255) / 256, 256, 0, stream>>>(counts, dis);

    // CSR build
    scan1_kernel<<<NB, 256, 0, stream>>>(counts, offsets, blocksums);
    scan2_kernel<<<1, 64, 0, stream>>>(blocksums, NB);
    scan3_kernel<<<(NN + 255) / 256, 256, 0, stream>>>(offsets, cursor, blocksums);
    scatter_kernel<<<(EE + 255) / 256, 256, 0, stream>>>(src, dst, cursor, sorted_src);

    // layer 1
    gemm1_kernel<<<NN / 4, 256, 0, stream>>>(x, W1, xt1);
    agg1_csr_kernel<<<(NN + 3) / 4, 256, 0, stream>>>(offsets, cursor, sorted_src, dis, xt1, b1, h1);

    // layer 2
    gemm2_kernel<<<(NN + 255) / 256, 256, 0, stream>>>(h1, W2, xt2);
    agg2_final_kernel<<<(NN + 255) / 256, 256, 0, stream>>>(offsets, cursor, sorted_src, dis, xt2, b2, out);
}

// Round 3
// 466.574 us; speedup vs baseline: 4.4033x; 1.5489x over previous
//
#include <hip/hip_runtime.h>
#include <hip/hip_bf16.h>

#define NN 100000
#define EE 1600000
#define IN_DIM 512
#define HID 64
#define SCAN_CHUNK 1024

// ---------------- degree histogram (int) ----------------
__global__ void deg_kernel(const int* __restrict__ dst, int* __restrict__ counts) {
    int e = blockIdx.x * 256 + threadIdx.x;
    if (e < EE) atomicAdd(&counts[dst[e]], 1);
}

__global__ void dis_kernel(const int* __restrict__ counts, float* __restrict__ dis) {
    int i = blockIdx.x * 256 + threadIdx.x;
    if (i < NN) dis[i] = rsqrtf((float)counts[i] + 1.0f);  // +1 self-loop
}

// ---------------- 3-kernel exclusive scan over counts -> offsets ----------------
__global__ void scan1_kernel(const int* __restrict__ counts, int* __restrict__ offsets,
                             int* __restrict__ blocksums) {
    __shared__ int lds[256];
    const int t = threadIdx.x;
    const int base = blockIdx.x * SCAN_CHUNK + t * 4;
    int v[4];
    int s = 0;
#pragma unroll
    for (int k = 0; k < 4; ++k) {
        v[k] = (base + k < NN) ? counts[base + k] : 0;
        s += v[k];
    }
    lds[t] = s;
    __syncthreads();
    for (int off = 1; off < 256; off <<= 1) {
        int add = (t >= off) ? lds[t - off] : 0;
        __syncthreads();
        lds[t] += add;
        __syncthreads();
    }
    int excl = lds[t] - s;
    if (t == 255) blocksums[blockIdx.x] = lds[t];
    int run = excl;
#pragma unroll
    for (int k = 0; k < 4; ++k) {
        if (base + k < NN) offsets[base + k] = run;
        run += v[k];
    }
}

__global__ void scan2_kernel(int* __restrict__ blocksums, int nb) {
    if (threadIdx.x == 0) {
        int run = 0;
        for (int i = 0; i < nb; ++i) { int v = blocksums[i]; blocksums[i] = run; run += v; }
    }
}

__global__ void scan3_kernel(int* __restrict__ offsets, int* __restrict__ cursor,
                             const int* __restrict__ blocksums) {
    int i = blockIdx.x * 256 + threadIdx.x;
    if (i < NN) {
        int v = offsets[i] + blocksums[i >> 10];
        offsets[i] = v;
        cursor[i] = v;
    }
}

// ---------------- scatter edges into CSR (sorted by dst) ----------------
__global__ void scatter_kernel(const int* __restrict__ src, const int* __restrict__ dst,
                               int* __restrict__ cursor, int* __restrict__ sorted_src) {
    int e = blockIdx.x * 256 + threadIdx.x;
    if (e >= EE) return;
    int d = dst[e];
    int pos = atomicAdd(&cursor[d], 1);
    sorted_src[pos] = src[e];
}
// after scatter: cursor[i] == end of segment i, offsets[i] == start

// ---------------- GEMM1: xt1 = x @ W1  [N,512]x[512,64] ----------------
// 64 rows x 128 k LDS tile; thread = 4x4 output tile (16 indep accumulators)
#define BM 64
#define BK 128
#define XPAD 4
__global__ __launch_bounds__(256) void gemm1_kernel(const float* __restrict__ x,
                                                    const float* __restrict__ W1,
                                                    float* __restrict__ xt1) {
    __shared__ float xs[BM][BK + XPAD];   // 64*132*4 = 33 KB
    const int tid = threadIdx.x;
    const int row0 = blockIdx.x * BM;
    const int cg = tid & 15;        // cols cg*4 .. cg*4+3
    const int rg = tid >> 4;        // rows rg*4 .. rg*4+3
    float acc[4][4] = {};

    for (int kt = 0; kt < IN_DIM; kt += BK) {
        __syncthreads();
        // stage 64 rows x 128 k = 2048 float4; 8 per thread, coalesced along k
#pragma unroll
        for (int i = 0; i < 8; ++i) {
            int idx = tid + i * 256;
            int r = idx >> 5;                 // 32 float4 per row
            int k4 = idx & 31;
            int rr = min(row0 + r, NN - 1);   // clamp for last partial block
            float4 v = *(const float4*)(x + (size_t)rr * IN_DIM + kt + k4 * 4);
            *(float4*)&xs[r][k4 * 4] = v;
        }
        __syncthreads();
#pragma unroll 8
        for (int k = 0; k < BK; ++k) {
            float4 w = *(const float4*)(W1 + (size_t)(kt + k) * HID + cg * 4);
#pragma unroll
            for (int i = 0; i < 4; ++i) {
                float xv = xs[rg * 4 + i][k];
                acc[i][0] += xv * w.x;
                acc[i][1] += xv * w.y;
                acc[i][2] += xv * w.z;
                acc[i][3] += xv * w.w;
            }
        }
    }
#pragma unroll
    for (int i = 0; i < 4; ++i) {
        int r = row0 + rg * 4 + i;
        if (r < NN)
            *(float4*)(xt1 + (size_t)r * HID + cg * 4) =
                make_float4(acc[i][0], acc[i][1], acc[i][2], acc[i][3]);
    }
}

// ---------------- pull aggregation layer1 (wave per node) + fused epilogue ----
__global__ void agg1_csr_kernel(const int* __restrict__ offsets, const int* __restrict__ cursor,
                                const int* __restrict__ sorted_src,
                                const float* __restrict__ dis,
                                const float* __restrict__ xt1,
                                const float* __restrict__ b1,
                                float* __restrict__ h1) {
    int node = blockIdx.x * 4 + (threadIdx.x >> 6);
    if (node >= NN) return;
    int lane = threadIdx.x & 63;
    int beg = offsets[node], end = cursor[node];
    float dd = dis[node];
    float acc = xt1[(size_t)node * HID + lane] * (dd * dd);  // self-loop
    for (int base = beg; base < end; base += 64) {
        int m = min(64, end - base);
        int s = 0;
        float nd = 0.f;
        if (lane < m) {
            s = sorted_src[base + lane];   // coalesced batch load of edge list
            nd = dis[s];
        }
        for (int j = 0; j < m; ++j) {
            int sj = __shfl(s, j);
            float nj = __shfl(nd, j);
            acc += xt1[(size_t)sj * HID + lane] * (nj * dd);  // coalesced 256B row
        }
    }
    h1[(size_t)node * HID + lane] = fmaxf(acc + b1[lane], 0.f);
}

// ---------------- GEMM2: xt2 = h1 @ W2  [N,64]x[64,2] ----------------
__global__ void gemm2_kernel(const float* __restrict__ h1,
                             const float* __restrict__ W2,
                             float* __restrict__ xt2) {
    int i = blockIdx.x * 256 + threadIdx.x;
    if (i >= NN) return;
    const float4* hv = (const float4*)(h1 + (size_t)i * HID);
    float a0 = 0.f, a1 = 0.f;
#pragma unroll
    for (int k4 = 0; k4 < HID / 4; ++k4) {
        float4 h = hv[k4];
        int k = k4 * 4;
        a0 += h.x * W2[(k + 0) * 2 + 0] + h.y * W2[(k + 1) * 2 + 0]
            + h.z * W2[(k + 2) * 2 + 0] + h.w * W2[(k + 3) * 2 + 0];
        a1 += h.x * W2[(k + 0) * 2 + 1] + h.y * W2[(k + 1) * 2 + 1]
            + h.z * W2[(k + 2) * 2 + 1] + h.w * W2[(k + 3) * 2 + 1];
    }
    xt2[(size_t)i * 2 + 0] = a0;
    xt2[(size_t)i * 2 + 1] = a1;
}

// ---------------- pull aggregation layer2 + log_softmax (thread per node) ----
__global__ void agg2_final_kernel(const int* __restrict__ offsets, const int* __restrict__ cursor,
                                  const int* __restrict__ sorted_src,
                                  const float* __restrict__ dis,
                                  const float* __restrict__ xt2,
                                  const float* __restrict__ b2,
                                  float* __restrict__ out) {
    int node = blockIdx.x * 256 + threadIdx.x;
    if (node >= NN) return;
    int beg = offsets[node], end = cursor[node];
    float dd = dis[node];
    float d2 = dd * dd;
    float a0 = xt2[(size_t)node * 2 + 0] * d2;
    float a1 = xt2[(size_t)node * 2 + 1] * d2;
    for (int p = beg; p < end; ++p) {
        int s = sorted_src[p];
        float nrm = dis[s] * dd;
        float2 v = *(const float2*)(xt2 + (size_t)s * 2);
        a0 += v.x * nrm;
        a1 += v.y * nrm;
    }
    float v0 = a0 + b2[0], v1 = a1 + b2[1];
    float m = fmaxf(v0, v1);
    float lse = m + logf(expf(v0 - m) + expf(v1 - m));
    out[(size_t)node * 2 + 0] = v0 - lse;
    out[(size_t)node * 2 + 1] = v1 - lse;
}

extern "C" void kernel_launch(void* const* d_in, const int* in_sizes, int n_in,
                              void* d_out, int out_size, void* d_ws, size_t ws_size,
                              hipStream_t stream) {
    const float* x  = (const float*)d_in[0];
    const int* ei   = (const int*)d_in[1];
    const float* W1 = (const float*)d_in[2];
    const float* b1 = (const float*)d_in[3];
    const float* W2 = (const float*)d_in[4];
    const float* b2 = (const float*)d_in[5];
    const int* src = ei;
    const int* dst = ei + EE;
    float* out = (float*)d_out;

    // workspace layout
    float* ws         = (float*)d_ws;
    float* xt1        = ws;                                   // N*64
    float* h1         = xt1 + (size_t)NN * HID;               // N*64
    float* dis        = h1 + (size_t)NN * HID;                // N
    int*   counts     = (int*)(dis + NN);                     // N
    int*   offsets    = counts + NN;                          // N
    int*   cursor     = offsets + NN;                         // N
    int*   blocksums  = cursor + NN;                          // 128
    int*   sorted_src = blocksums + 128;                      // E
    float* xt2        = (float*)(sorted_src + EE);            // N*2

    const int NB = (NN + SCAN_CHUNK - 1) / SCAN_CHUNK;        // 98

    hipMemsetAsync(counts, 0, sizeof(int) * NN, stream);

    // degree + normalization
    deg_kernel<<<(EE + 255) / 256, 256, 0, stream>>>(dst, counts);
    dis_kernel<<<(NN + 255) / 256, 256, 0, stream>>>(counts, dis);

    // CSR build
    scan1_kernel<<<NB, 256, 0, stream>>>(counts, offsets, blocksums);
    scan2_kernel<<<1, 64, 0, stream>>>(blocksums, NB);
    scan3_kernel<<<(NN + 255) / 256, 256, 0, stream>>>(offsets, cursor, blocksums);
    scatter_kernel<<<(EE + 255) / 256, 256, 0, stream>>>(src, dst, cursor, sorted_src);

    // layer 1
    gemm1_kernel<<<(NN + BM - 1) / BM, 256, 0, stream>>>(x, W1, xt1);
    agg1_csr_kernel<<<(NN + 3) / 4, 256, 0, stream>>>(offsets, cursor, sorted_src, dis, xt1, b1, h1);

    // layer 2
    gemm2_kernel<<<(NN + 255) / 256, 256, 0, stream>>>(h1, W2, xt2);
    agg2_final_kernel<<<(NN + 255) / 256, 256, 0, stream>>>(offsets, cursor, sorted_src, dis, xt2, b2, out);
}

// Round 4
// 395.640 us; speedup vs baseline: 5.1928x; 1.1793x over previous
//
#include <hip/hip_runtime.h>
#include <hip/hip_bf16.h>

#define NN 100000
#define EE 1600000
#define IN_DIM 512
#define HID 64
#define SCAN_CHUNK 1024

typedef __attribute__((ext_vector_type(8))) short bf16x8;
typedef __attribute__((ext_vector_type(4))) float f32x4;

static __device__ __forceinline__ short f2bf(float f) {
    __hip_bfloat16 h = __float2bfloat16(f);
    return *reinterpret_cast<short*>(&h);
}

// ---------------- degree histogram (int) ----------------
__global__ void deg_kernel(const int* __restrict__ dst, int* __restrict__ counts) {
    int e = blockIdx.x * 256 + threadIdx.x;
    if (e < EE) atomicAdd(&counts[dst[e]], 1);
}

__global__ void dis_kernel(const int* __restrict__ counts, float* __restrict__ dis) {
    int i = blockIdx.x * 256 + threadIdx.x;
    if (i < NN) dis[i] = rsqrtf((float)counts[i] + 1.0f);  // +1 self-loop
}

// ---------------- 3-kernel exclusive scan over counts -> offsets ----------------
__global__ void scan1_kernel(const int* __restrict__ counts, int* __restrict__ offsets,
                             int* __restrict__ blocksums) {
    __shared__ int lds[256];
    const int t = threadIdx.x;
    const int base = blockIdx.x * SCAN_CHUNK + t * 4;
    int v[4];
    int s = 0;
#pragma unroll
    for (int k = 0; k < 4; ++k) {
        v[k] = (base + k < NN) ? counts[base + k] : 0;
        s += v[k];
    }
    lds[t] = s;
    __syncthreads();
    for (int off = 1; off < 256; off <<= 1) {
        int add = (t >= off) ? lds[t - off] : 0;
        __syncthreads();
        lds[t] += add;
        __syncthreads();
    }
    int excl = lds[t] - s;
    if (t == 255) blocksums[blockIdx.x] = lds[t];
    int run = excl;
#pragma unroll
    for (int k = 0; k < 4; ++k) {
        if (base + k < NN) offsets[base + k] = run;
        run += v[k];
    }
}

__global__ void scan2_kernel(int* __restrict__ blocksums, int nb) {
    if (threadIdx.x == 0) {
        int run = 0;
        for (int i = 0; i < nb; ++i) { int v = blocksums[i]; blocksums[i] = run; run += v; }
    }
}

__global__ void scan3_kernel(int* __restrict__ offsets, int* __restrict__ cursor,
                             const int* __restrict__ blocksums) {
    int i = blockIdx.x * 256 + threadIdx.x;
    if (i < NN) {
        int v = offsets[i] + blocksums[i >> 10];
        offsets[i] = v;
        cursor[i] = v;
    }
}

// ---------------- scatter edges into CSR (sorted by dst) ----------------
__global__ void scatter_kernel(const int* __restrict__ src, const int* __restrict__ dst,
                               int* __restrict__ cursor, int* __restrict__ sorted_src) {
    int e = blockIdx.x * 256 + threadIdx.x;
    if (e >= EE) return;
    int d = dst[e];
    int pos = atomicAdd(&cursor[d], 1);
    sorted_src[pos] = src[e];
}
// after scatter: cursor[i] == end of segment i, offsets[i] == start

// ---------------- W1 pack: fragment-ordered bf16 ----------------
// W1p element layout: [kstep 0..15][kb 0..3][col 0..63][j 0..7] where
// value = bf16(W1[kstep*32 + kb*8 + j][col]). One bf16x8 per (kstep,kb,col).
__global__ void packW1_kernel(const float* __restrict__ W1, bf16x8* __restrict__ W1p) {
    int t = blockIdx.x * 256 + threadIdx.x;   // 0..4095
    if (t >= 4096) return;
    int kstep = t >> 8;
    int kb = (t >> 6) & 3;
    int col = t & 63;
    int kbase = kstep * 32 + kb * 8;
    bf16x8 v;
#pragma unroll
    for (int j = 0; j < 8; ++j) v[j] = f2bf(W1[(size_t)(kbase + j) * HID + col]);
    W1p[t] = v;
}

// ---------------- GEMM1 (MFMA): xt1 = x @ W1  [N,512]x[512,64] ----------------
// wave = 16 rows x 64 cols; block = 4 waves = 64 rows. No LDS (rows wave-exclusive).
__global__ __launch_bounds__(256) void gemm1_kernel(const float* __restrict__ x,
                                                    const bf16x8* __restrict__ W1p,
                                                    float* __restrict__ xt1) {
    const int wave = threadIdx.x >> 6;
    const int lane = threadIdx.x & 63;
    const int r = lane & 15;        // A row within wave tile / B,C col
    const int kg = lane >> 4;       // k-group
    const int row0 = blockIdx.x * 64 + wave * 16;
    const int rowc = min(row0 + r, NN - 1);
    const float* xr = x + (size_t)rowc * IN_DIM;

    f32x4 acc[4] = {};
#pragma unroll
    for (int ks = 0; ks < 16; ++ks) {
        const int k0 = ks * 32 + kg * 8;
        float4 xa = *(const float4*)(xr + k0);
        float4 xb = *(const float4*)(xr + k0 + 4);
        bf16x8 a;
        a[0] = f2bf(xa.x); a[1] = f2bf(xa.y); a[2] = f2bf(xa.z); a[3] = f2bf(xa.w);
        a[4] = f2bf(xb.x); a[5] = f2bf(xb.y); a[6] = f2bf(xb.z); a[7] = f2bf(xb.w);
        const int bbase = (ks * 4 + kg) * 64;
#pragma unroll
        for (int cb = 0; cb < 4; ++cb) {
            bf16x8 b = W1p[bbase + cb * 16 + r];
            acc[cb] = __builtin_amdgcn_mfma_f32_16x16x32_bf16(a, b, acc[cb], 0, 0, 0);
        }
    }
    // C/D: col = lane&15 (=r), row = kg*4 + reg
#pragma unroll
    for (int cb = 0; cb < 4; ++cb) {
#pragma unroll
        for (int reg = 0; reg < 4; ++reg) {
            int ro = row0 + kg * 4 + reg;
            if (ro < NN) xt1[(size_t)ro * HID + cb * 16 + r] = acc[cb][reg];
        }
    }
}

// ---------------- pull aggregation layer1 (wave per node) + fused epilogue ----
__global__ void agg1_csr_kernel(const int* __restrict__ offsets, const int* __restrict__ cursor,
                                const int* __restrict__ sorted_src,
                                const float* __restrict__ dis,
                                const float* __restrict__ xt1,
                                const float* __restrict__ b1,
                                float* __restrict__ h1) {
    int node = blockIdx.x * 4 + (threadIdx.x >> 6);
    if (node >= NN) return;
    int lane = threadIdx.x & 63;
    int beg = offsets[node], end = cursor[node];
    float dd = dis[node];
    float acc = xt1[(size_t)node * HID + lane] * (dd * dd);  // self-loop
    for (int base = beg; base < end; base += 64) {
        int m = min(64, end - base);
        int s = 0;
        float nd = 0.f;
        if (lane < m) {
            s = sorted_src[base + lane];   // coalesced batch load of edge list
            nd = dis[s];
        }
        for (int j = 0; j < m; ++j) {
            int sj = __shfl(s, j);
            float nj = __shfl(nd, j);
            acc += xt1[(size_t)sj * HID + lane] * (nj * dd);  // coalesced 256B row
        }
    }
    h1[(size_t)node * HID + lane] = fmaxf(acc + b1[lane], 0.f);
}

// ---------------- GEMM2: xt2 = h1 @ W2  [N,64]x[64,2] ----------------
__global__ void gemm2_kernel(const float* __restrict__ h1,
                             const float* __restrict__ W2,
                             float* __restrict__ xt2) {
    int i = blockIdx.x * 256 + threadIdx.x;
    if (i >= NN) return;
    const float4* hv = (const float4*)(h1 + (size_t)i * HID);
    float a0 = 0.f, a1 = 0.f;
#pragma unroll
    for (int k4 = 0; k4 < HID / 4; ++k4) {
        float4 h = hv[k4];
        int k = k4 * 4;
        a0 += h.x * W2[(k + 0) * 2 + 0] + h.y * W2[(k + 1) * 2 + 0]
            + h.z * W2[(k + 2) * 2 + 0] + h.w * W2[(k + 3) * 2 + 0];
        a1 += h.x * W2[(k + 0) * 2 + 1] + h.y * W2[(k + 1) * 2 + 1]
            + h.z * W2[(k + 2) * 2 + 1] + h.w * W2[(k + 3) * 2 + 1];
    }
    xt2[(size_t)i * 2 + 0] = a0;
    xt2[(size_t)i * 2 + 1] = a1;
}

// ---------------- pull aggregation layer2 + log_softmax (thread per node) ----
__global__ void agg2_final_kernel(const int* __restrict__ offsets, const int* __restrict__ cursor,
                                  const int* __restrict__ sorted_src,
                                  const float* __restrict__ dis,
                                  const float* __restrict__ xt2,
                                  const float* __restrict__ b2,
                                  float* __restrict__ out) {
    int node = blockIdx.x * 256 + threadIdx.x;
    if (node >= NN) return;
    int beg = offsets[node], end = cursor[node];
    float dd = dis[node];
    float d2 = dd * dd;
    float a0 = xt2[(size_t)node * 2 + 0] * d2;
    float a1 = xt2[(size_t)node * 2 + 1] * d2;
    for (int p = beg; p < end; ++p) {
        int s = sorted_src[p];
        float nrm = dis[s] * dd;
        float2 v = *(const float2*)(xt2 + (size_t)s * 2);
        a0 += v.x * nrm;
        a1 += v.y * nrm;
    }
    float v0 = a0 + b2[0], v1 = a1 + b2[1];
    float m = fmaxf(v0, v1);
    float lse = m + logf(expf(v0 - m) + expf(v1 - m));
    out[(size_t)node * 2 + 0] = v0 - lse;
    out[(size_t)node * 2 + 1] = v1 - lse;
}

extern "C" void kernel_launch(void* const* d_in, const int* in_sizes, int n_in,
                              void* d_out, int out_size, void* d_ws, size_t ws_size,
                              hipStream_t stream) {
    const float* x  = (const float*)d_in[0];
    const int* ei   = (const int*)d_in[1];
    const float* W1 = (const float*)d_in[2];
    const float* b1 = (const float*)d_in[3];
    const float* W2 = (const float*)d_in[4];
    const float* b2 = (const float*)d_in[5];
    const int* src = ei;
    const int* dst = ei + EE;
    float* out = (float*)d_out;

    // workspace layout
    float* ws         = (float*)d_ws;
    float* xt1        = ws;                                   // N*64
    float* h1         = xt1 + (size_t)NN * HID;               // N*64
    float* dis        = h1 + (size_t)NN * HID;                // N
    int*   counts     = (int*)(dis + NN);                     // N
    int*   offsets    = counts + NN;                          // N
    int*   cursor     = offsets + NN;                         // N
    int*   blocksums  = cursor + NN;                          // 128
    int*   sorted_src = blocksums + 128;                      // E
    float* xt2        = (float*)(sorted_src + EE);            // N*2
    bf16x8* W1p       = (bf16x8*)(xt2 + (size_t)NN * 2);      // 4096 * 16B = 64 KB

    const int NB = (NN + SCAN_CHUNK - 1) / SCAN_CHUNK;        // 98

    hipMemsetAsync(counts, 0, sizeof(int) * NN, stream);

    // degree + normalization + W1 pack
    deg_kernel<<<(EE + 255) / 256, 256, 0, stream>>>(dst, counts);
    dis_kernel<<<(NN + 255) / 256, 256, 0, stream>>>(counts, dis);
    packW1_kernel<<<16, 256, 0, stream>>>(W1, W1p);

    // CSR build
    scan1_kernel<<<NB, 256, 0, stream>>>(counts, offsets, blocksums);
    scan2_kernel<<<1, 64, 0, stream>>>(blocksums, NB);
    scan3_kernel<<<(NN + 255) / 256, 256, 0, stream>>>(offsets, cursor, blocksums);
    scatter_kernel<<<(EE + 255) / 256, 256, 0, stream>>>(src, dst, cursor, sorted_src);

    // layer 1
    gemm1_kernel<<<(NN + 63) / 64, 256, 0, stream>>>(x, W1p, xt1);
    agg1_csr_kernel<<<(NN + 3) / 4, 256, 0, stream>>>(offsets, cursor, sorted_src, dis, xt1, b1, h1);

    // layer 2
    gemm2_kernel<<<(NN + 255) / 256, 256, 0, stream>>>(h1, W2, xt2);
    agg2_final_kernel<<<(NN + 255) / 256, 256, 0, stream>>>(offsets, cursor, sorted_src, dis, xt2, b2, out);
}

// Round 5
// 285.943 us; speedup vs baseline: 7.1849x; 1.3836x over previous
//
#include <hip/hip_runtime.h>
#include <hip/hip_bf16.h>

#define NN 100000
#define EE 1600000
#define IN_DIM 512
#define HID 64
#define NB1 196          // coarse buckets (512 nodes each)
#define NCH 98           // chunks
#define CHUNK 16384      // edges per chunk (98*16384 >= EE)

typedef __attribute__((ext_vector_type(8))) short bf16x8;
typedef __attribute__((ext_vector_type(4))) float f32x4;

static __device__ __forceinline__ short f2bf(float f) {
    __hip_bfloat16 h = __float2bfloat16(f);
    return *reinterpret_cast<short*>(&h);
}

// ---------------- pass 1a: per-chunk coarse histogram ----------------
__global__ __launch_bounds__(256) void hist1a_kernel(const int* __restrict__ dst,
                                                     int* __restrict__ cnt2d) {
    __shared__ int h[NB1];
    const int t = threadIdx.x;
    for (int i = t; i < NB1; i += 256) h[i] = 0;
    __syncthreads();
    const int base = blockIdx.x * CHUNK;
    for (int i = t; i < CHUNK; i += 256) {
        int e = base + i;
        if (e < EE) atomicAdd(&h[dst[e] >> 9], 1);
    }
    __syncthreads();
    for (int i = t; i < NB1; i += 256) cnt2d[blockIdx.x * NB1 + i] = h[i];
}

// ---------------- pass 1b: 2D scan -> per-(chunk,bucket) bases ----------------
__global__ __launch_bounds__(256) void scan1b_kernel(const int* __restrict__ cnt2d,
                                                     int* __restrict__ base2d,
                                                     int* __restrict__ coarse) {
    __shared__ int tot[NB1];
    __shared__ int off[NB1 + 1];
    const int t = threadIdx.x;
    if (t < NB1) {
        int s = 0;
        for (int c = 0; c < NCH; ++c) s += cnt2d[c * NB1 + t];
        tot[t] = s;
    }
    __syncthreads();
    if (t == 0) {
        int run = 0;
        for (int b = 0; b < NB1; ++b) { off[b] = run; run += tot[b]; }
        off[NB1] = run;   // == EE
    }
    __syncthreads();
    if (t < NB1) {
        int run = off[t];
        for (int c = 0; c < NCH; ++c) {
            base2d[c * NB1 + t] = run;
            run += cnt2d[c * NB1 + t];
        }
    }
    if (t <= NB1) coarse[t] = off[t];
}

// ---------------- pass 1c: bucketed scatter of (src,dst) pairs ----------------
__global__ __launch_bounds__(256) void scatter1c_kernel(const int* __restrict__ src,
                                                        const int* __restrict__ dst,
                                                        const int* __restrict__ base2d,
                                                        int2* __restrict__ pairs) {
    __shared__ int cur[NB1];
    const int t = threadIdx.x;
    for (int i = t; i < NB1; i += 256) cur[i] = base2d[blockIdx.x * NB1 + i];
    __syncthreads();
    const int base = blockIdx.x * CHUNK;
    for (int i = t; i < CHUNK; i += 256) {
        int e = base + i;
        if (e < EE) {
            int s = src[e], d = dst[e];
            int pos = atomicAdd(&cur[d >> 9], 1);
            pairs[pos] = make_int2(s, d);
        }
    }
}

// ---------------- pass 2: per-bucket exact CSR sort + deg/dis/offsets ----------
__global__ __launch_bounds__(256) void sort2_kernel(const int2* __restrict__ pairs,
                                                    const int* __restrict__ coarse,
                                                    int* __restrict__ offsets,
                                                    int* __restrict__ cursor,
                                                    int* __restrict__ sorted_src,
                                                    float* __restrict__ dis) {
    __shared__ int sdeg[512];
    __shared__ int sinc[512];
    __shared__ int scur[512];
    const int b = blockIdx.x;
    const int t = threadIdx.x;
    const int n0 = b << 9;
    const int nn = min(512, NN - n0);
    const int e0 = coarse[b], e1 = coarse[b + 1];

    sdeg[t] = 0; sdeg[t + 256] = 0;
    __syncthreads();
    for (int e = e0 + t; e < e1; e += 256)
        atomicAdd(&sdeg[pairs[e].y - n0], 1);
    __syncthreads();
    // inclusive Hillis-Steele scan over 512 elems with 256 threads
    sinc[t] = sdeg[t]; sinc[t + 256] = sdeg[t + 256];
    __syncthreads();
    for (int off = 1; off < 512; off <<= 1) {
        int v0 = (t >= off) ? sinc[t - off] : 0;
        int v1 = (t + 256 >= off) ? sinc[t + 256 - off] : 0;
        __syncthreads();
        sinc[t] += v0; sinc[t + 256] += v1;
        __syncthreads();
    }
#pragma unroll
    for (int k = 0; k < 2; ++k) {
        int n = t + k * 256;
        int excl = sinc[n] - sdeg[n];
        scur[n] = excl;
        if (n < nn) {
            offsets[n0 + n] = e0 + excl;
            cursor[n0 + n]  = e0 + excl + sdeg[n];
            dis[n0 + n]     = rsqrtf((float)sdeg[n] + 1.0f);
        }
    }
    __syncthreads();
    for (int e = e0 + t; e < e1; e += 256) {
        int2 p = pairs[e];
        int pos = atomicAdd(&scur[p.y - n0], 1);
        sorted_src[e0 + pos] = p.x;
    }
}

// ---------------- W1 pack: fragment-ordered bf16 ----------------
__global__ void packW1_kernel(const float* __restrict__ W1, bf16x8* __restrict__ W1p) {
    int t = blockIdx.x * 256 + threadIdx.x;   // 0..4095
    if (t >= 4096) return;
    int kstep = t >> 8;
    int kb = (t >> 6) & 3;
    int col = t & 63;
    int kbase = kstep * 32 + kb * 8;
    bf16x8 v;
#pragma unroll
    for (int j = 0; j < 8; ++j) v[j] = f2bf(W1[(size_t)(kbase + j) * HID + col]);
    W1p[t] = v;
}

// ---------------- GEMM1 (MFMA): xt1 = x @ W1  [N,512]x[512,64] ----------------
__global__ __launch_bounds__(256) void gemm1_kernel(const float* __restrict__ x,
                                                    const bf16x8* __restrict__ W1p,
                                                    float* __restrict__ xt1) {
    const int wave = threadIdx.x >> 6;
    const int lane = threadIdx.x & 63;
    const int r = lane & 15;        // A row within wave tile / B,C col
    const int kg = lane >> 4;       // k-group
    const int row0 = blockIdx.x * 64 + wave * 16;
    const int rowc = min(row0 + r, NN - 1);
    const float* xr = x + (size_t)rowc * IN_DIM;

    f32x4 acc[4] = {};
#pragma unroll
    for (int ks = 0; ks < 16; ++ks) {
        const int k0 = ks * 32 + kg * 8;
        float4 xa = *(const float4*)(xr + k0);
        float4 xb = *(const float4*)(xr + k0 + 4);
        bf16x8 a;
        a[0] = f2bf(xa.x); a[1] = f2bf(xa.y); a[2] = f2bf(xa.z); a[3] = f2bf(xa.w);
        a[4] = f2bf(xb.x); a[5] = f2bf(xb.y); a[6] = f2bf(xb.z); a[7] = f2bf(xb.w);
        const int bbase = (ks * 4 + kg) * 64;
#pragma unroll
        for (int cb = 0; cb < 4; ++cb) {
            bf16x8 bfr = W1p[bbase + cb * 16 + r];
            acc[cb] = __builtin_amdgcn_mfma_f32_16x16x32_bf16(a, bfr, acc[cb], 0, 0, 0);
        }
    }
#pragma unroll
    for (int cb = 0; cb < 4; ++cb) {
#pragma unroll
        for (int reg = 0; reg < 4; ++reg) {
            int ro = row0 + kg * 4 + reg;
            if (ro < NN) xt1[(size_t)ro * HID + cb * 16 + r] = acc[cb][reg];
        }
    }
}

// ---------------- pull aggregation layer1 (wave per node) + fused epilogue ----
__global__ void agg1_csr_kernel(const int* __restrict__ offsets, const int* __restrict__ cursor,
                                const int* __restrict__ sorted_src,
                                const float* __restrict__ dis,
                                const float* __restrict__ xt1,
                                const float* __restrict__ b1,
                                float* __restrict__ h1) {
    int node = blockIdx.x * 4 + (threadIdx.x >> 6);
    if (node >= NN) return;
    int lane = threadIdx.x & 63;
    int beg = offsets[node], end = cursor[node];
    float dd = dis[node];
    float acc = xt1[(size_t)node * HID + lane] * (dd * dd);  // self-loop
    for (int base = beg; base < end; base += 64) {
        int m = min(64, end - base);
        int s = 0;
        float nd = 0.f;
        if (lane < m) {
            s = sorted_src[base + lane];
            nd = dis[s];
        }
        for (int j = 0; j < m; ++j) {
            int sj = __shfl(s, j);
            float nj = __shfl(nd, j);
            acc += xt1[(size_t)sj * HID + lane] * (nj * dd);
        }
    }
    h1[(size_t)node * HID + lane] = fmaxf(acc + b1[lane], 0.f);
}

// ---------------- GEMM2: xt2 = h1 @ W2  [N,64]x[64,2] ----------------
__global__ void gemm2_kernel(const float* __restrict__ h1,
                             const float* __restrict__ W2,
                             float* __restrict__ xt2) {
    int i = blockIdx.x * 256 + threadIdx.x;
    if (i >= NN) return;
    const float4* hv = (const float4*)(h1 + (size_t)i * HID);
    float a0 = 0.f, a1 = 0.f;
#pragma unroll
    for (int k4 = 0; k4 < HID / 4; ++k4) {
        float4 h = hv[k4];
        int k = k4 * 4;
        a0 += h.x * W2[(k + 0) * 2 + 0] + h.y * W2[(k + 1) * 2 + 0]
            + h.z * W2[(k + 2) * 2 + 0] + h.w * W2[(k + 3) * 2 + 0];
        a1 += h.x * W2[(k + 0) * 2 + 1] + h.y * W2[(k + 1) * 2 + 1]
            + h.z * W2[(k + 2) * 2 + 1] + h.w * W2[(k + 3) * 2 + 1];
    }
    xt2[(size_t)i * 2 + 0] = a0;
    xt2[(size_t)i * 2 + 1] = a1;
}

// ---------------- pull aggregation layer2 + log_softmax (thread per node) ----
__global__ void agg2_final_kernel(const int* __restrict__ offsets, const int* __restrict__ cursor,
                                  const int* __restrict__ sorted_src,
                                  const float* __restrict__ dis,
                                  const float* __restrict__ xt2,
                                  const float* __restrict__ b2,
                                  float* __restrict__ out) {
    int node = blockIdx.x * 256 + threadIdx.x;
    if (node >= NN) return;
    int beg = offsets[node], end = cursor[node];
    float dd = dis[node];
    float d2 = dd * dd;
    float a0 = xt2[(size_t)node * 2 + 0] * d2;
    float a1 = xt2[(size_t)node * 2 + 1] * d2;
    for (int p = beg; p < end; ++p) {
        int s = sorted_src[p];
        float nrm = dis[s] * dd;
        float2 v = *(const float2*)(xt2 + (size_t)s * 2);
        a0 += v.x * nrm;
        a1 += v.y * nrm;
    }
    float v0 = a0 + b2[0], v1 = a1 + b2[1];
    float m = fmaxf(v0, v1);
    float lse = m + logf(expf(v0 - m) + expf(v1 - m));
    out[(size_t)node * 2 + 0] = v0 - lse;
    out[(size_t)node * 2 + 1] = v1 - lse;
}

extern "C" void kernel_launch(void* const* d_in, const int* in_sizes, int n_in,
                              void* d_out, int out_size, void* d_ws, size_t ws_size,
                              hipStream_t stream) {
    const float* x  = (const float*)d_in[0];
    const int* ei   = (const int*)d_in[1];
    const float* W1 = (const float*)d_in[2];
    const float* b1 = (const float*)d_in[3];
    const float* W2 = (const float*)d_in[4];
    const float* b2 = (const float*)d_in[5];
    const int* src = ei;
    const int* dst = ei + EE;
    float* out = (float*)d_out;

    // workspace layout
    float* ws         = (float*)d_ws;
    float* xt1        = ws;                                   // N*64
    float* h1         = xt1 + (size_t)NN * HID;               // N*64 (aliased as pairs first)
    float* dis        = h1 + (size_t)NN * HID;                // N
    int*   offsets    = (int*)(dis + NN);                     // N
    int*   cursor     = offsets + NN;                         // N
    int*   sorted_src = cursor + NN;                          // E
    float* xt2        = (float*)(sorted_src + EE);            // N*2
    bf16x8* W1p       = (bf16x8*)(xt2 + (size_t)NN * 2);      // 4096*16B
    int*   cnt2d      = (int*)(W1p + 4096);                   // NCH*NB1
    int*   base2d     = cnt2d + NCH * NB1;                    // NCH*NB1
    int*   coarse     = base2d + NCH * NB1;                   // NB1+1
    int2*  pairs      = (int2*)h1;                            // E*8B, dead before h1 written

    // CSR build (two-level counting sort by dst; also produces dis/offsets/cursor)
    hist1a_kernel<<<NCH, 256, 0, stream>>>(dst, cnt2d);
    scan1b_kernel<<<1, 256, 0, stream>>>(cnt2d, base2d, coarse);
    scatter1c_kernel<<<NCH, 256, 0, stream>>>(src, dst, base2d, pairs);
    sort2_kernel<<<NB1, 256, 0, stream>>>(pairs, coarse, offsets, cursor, sorted_src, dis);

    // layer 1
    packW1_kernel<<<16, 256, 0, stream>>>(W1, W1p);
    gemm1_kernel<<<(NN + 63) / 64, 256, 0, stream>>>(x, W1p, xt1);
    agg1_csr_kernel<<<(NN + 3) / 4, 256, 0, stream>>>(offsets, cursor, sorted_src, dis, xt1, b1, h1);

    // layer 2
    gemm2_kernel<<<(NN + 255) / 256, 256, 0, stream>>>(h1, W2, xt2);
    agg2_final_kernel<<<(NN + 255) / 256, 256, 0, stream>>>(offsets, cursor, sorted_src, dis, xt2, b2, out);
}

// Round 6
// 250.809 us; speedup vs baseline: 8.1913x; 1.1401x over previous
//
#include <hip/hip_runtime.h>
#include <hip/hip_bf16.h>

#define NN 100000
#define EE 1600000
#define IN_DIM 512
#define HID 64
#define NB1 196          // coarse buckets (512 nodes each)
#define NCH 391          // chunks
#define CHUNK 4096       // edges per chunk (391*4096 >= EE)

typedef __attribute__((ext_vector_type(8))) short bf16x8;
typedef __attribute__((ext_vector_type(4))) float f32x4;

static __device__ __forceinline__ short f2bf(float f) {
    __hip_bfloat16 h = __float2bfloat16(f);
    return *reinterpret_cast<short*>(&h);
}
static __device__ __forceinline__ float bf2f(unsigned short u) {
    unsigned int v = ((unsigned int)u) << 16;
    union { unsigned int i; float f; } c; c.i = v;
    return c.f;
}

// ---------------- pass 1a: per-chunk coarse histogram ----------------
__global__ __launch_bounds__(256) void hist1a_kernel(const int* __restrict__ dst,
                                                     int* __restrict__ cnt2d) {
    __shared__ int h[NB1];
    const int t = threadIdx.x;
    for (int i = t; i < NB1; i += 256) h[i] = 0;
    __syncthreads();
    const int base = blockIdx.x * CHUNK;
    for (int i = t; i < CHUNK; i += 256) {
        int e = base + i;
        if (e < EE) atomicAdd(&h[dst[e] >> 9], 1);
    }
    __syncthreads();
    for (int i = t; i < NB1; i += 256) cnt2d[blockIdx.x * NB1 + i] = h[i];
}

// ---------------- pass 1b: 2D scan -> per-(chunk,bucket) bases ----------------
__global__ __launch_bounds__(256) void scan1b_kernel(const int* __restrict__ cnt2d,
                                                     int* __restrict__ base2d,
                                                     int* __restrict__ coarse) {
    __shared__ int tot[NB1];
    __shared__ int off[NB1 + 1];
    const int t = threadIdx.x;
    if (t < NB1) {
        int s = 0;
        for (int c = 0; c < NCH; ++c) s += cnt2d[c * NB1 + t];
        tot[t] = s;
    }
    __syncthreads();
    if (t == 0) {
        int run = 0;
        for (int b = 0; b < NB1; ++b) { off[b] = run; run += tot[b]; }
        off[NB1] = run;   // == EE
    }
    __syncthreads();
    if (t < NB1) {
        int run = off[t];
        for (int c = 0; c < NCH; ++c) {
            base2d[c * NB1 + t] = run;
            run += cnt2d[c * NB1 + t];
        }
    }
    if (t <= NB1) coarse[t] = off[t];
}

// ---------------- pass 1c: bucketed scatter of (src,dst) pairs ----------------
__global__ __launch_bounds__(256) void scatter1c_kernel(const int* __restrict__ src,
                                                        const int* __restrict__ dst,
                                                        const int* __restrict__ base2d,
                                                        int2* __restrict__ pairs) {
    __shared__ int cur[NB1];
    const int t = threadIdx.x;
    for (int i = t; i < NB1; i += 256) cur[i] = base2d[blockIdx.x * NB1 + i];
    __syncthreads();
    const int base = blockIdx.x * CHUNK;
    for (int i = t; i < CHUNK; i += 256) {
        int e = base + i;
        if (e < EE) {
            int s = src[e], d = dst[e];
            int pos = atomicAdd(&cur[d >> 9], 1);
            pairs[pos] = make_int2(s, d);
        }
    }
}

// ---------------- pass 2: per-bucket exact CSR sort + deg/dis/offsets ----------
__global__ __launch_bounds__(256) void sort2_kernel(const int2* __restrict__ pairs,
                                                    const int* __restrict__ coarse,
                                                    int* __restrict__ offsets,
                                                    int* __restrict__ cursor,
                                                    int* __restrict__ sorted_src,
                                                    float* __restrict__ dis) {
    __shared__ int sdeg[512];
    __shared__ int sinc[512];
    __shared__ int scur[512];
    const int b = blockIdx.x;
    const int t = threadIdx.x;
    const int n0 = b << 9;
    const int nn = min(512, NN - n0);
    const int e0 = coarse[b], e1 = coarse[b + 1];

    sdeg[t] = 0; sdeg[t + 256] = 0;
    __syncthreads();
    for (int e = e0 + t; e < e1; e += 256)
        atomicAdd(&sdeg[pairs[e].y - n0], 1);
    __syncthreads();
    // inclusive Hillis-Steele scan over 512 elems with 256 threads
    sinc[t] = sdeg[t]; sinc[t + 256] = sdeg[t + 256];
    __syncthreads();
    for (int off = 1; off < 512; off <<= 1) {
        int v0 = (t >= off) ? sinc[t - off] : 0;
        int v1 = (t + 256 >= off) ? sinc[t + 256 - off] : 0;
        __syncthreads();
        sinc[t] += v0; sinc[t + 256] += v1;
        __syncthreads();
    }
#pragma unroll
    for (int k = 0; k < 2; ++k) {
        int n = t + k * 256;
        int excl = sinc[n] - sdeg[n];
        scur[n] = excl;
        if (n < nn) {
            offsets[n0 + n] = e0 + excl;
            cursor[n0 + n]  = e0 + excl + sdeg[n];
            dis[n0 + n]     = rsqrtf((float)sdeg[n] + 1.0f);
        }
    }
    __syncthreads();
    for (int e = e0 + t; e < e1; e += 256) {
        int2 p = pairs[e];
        int pos = atomicAdd(&scur[p.y - n0], 1);
        sorted_src[e0 + pos] = p.x;
    }
}

// ---------------- W1 pack: fragment-ordered bf16 ----------------
__global__ void packW1_kernel(const float* __restrict__ W1, bf16x8* __restrict__ W1p) {
    int t = blockIdx.x * 256 + threadIdx.x;   // 0..4095
    if (t >= 4096) return;
    int kstep = t >> 8;
    int kb = (t >> 6) & 3;
    int col = t & 63;
    int kbase = kstep * 32 + kb * 8;
    bf16x8 v;
#pragma unroll
    for (int j = 0; j < 8; ++j) v[j] = f2bf(W1[(size_t)(kbase + j) * HID + col]);
    W1p[t] = v;
}

// ---------------- GEMM1 (MFMA): xt1b = bf16(x @ W1)  [N,512]x[512,64] --------
__global__ __launch_bounds__(256) void gemm1_kernel(const float* __restrict__ x,
                                                    const bf16x8* __restrict__ W1p,
                                                    unsigned short* __restrict__ xt1b) {
    const int wave = threadIdx.x >> 6;
    const int lane = threadIdx.x & 63;
    const int r = lane & 15;        // A row within wave tile / B,C col
    const int kg = lane >> 4;       // k-group
    const int row0 = blockIdx.x * 64 + wave * 16;
    const int rowc = min(row0 + r, NN - 1);
    const float* xr = x + (size_t)rowc * IN_DIM;

    f32x4 acc[4] = {};
#pragma unroll
    for (int ks = 0; ks < 16; ++ks) {
        const int k0 = ks * 32 + kg * 8;
        float4 xa = *(const float4*)(xr + k0);
        float4 xb = *(const float4*)(xr + k0 + 4);
        bf16x8 a;
        a[0] = f2bf(xa.x); a[1] = f2bf(xa.y); a[2] = f2bf(xa.z); a[3] = f2bf(xa.w);
        a[4] = f2bf(xb.x); a[5] = f2bf(xb.y); a[6] = f2bf(xb.z); a[7] = f2bf(xb.w);
        const int bbase = (ks * 4 + kg) * 64;
#pragma unroll
        for (int cb = 0; cb < 4; ++cb) {
            bf16x8 bfr = W1p[bbase + cb * 16 + r];
            acc[cb] = __builtin_amdgcn_mfma_f32_16x16x32_bf16(a, bfr, acc[cb], 0, 0, 0);
        }
    }
    // C/D: col = lane&15 (=r), row = kg*4 + reg
#pragma unroll
    for (int cb = 0; cb < 4; ++cb) {
#pragma unroll
        for (int reg = 0; reg < 4; ++reg) {
            int ro = row0 + kg * 4 + reg;
            if (ro < NN) xt1b[(size_t)ro * HID + cb * 16 + r] =
                (unsigned short)f2bf(acc[cb][reg]);
        }
    }
}

// ------- pull aggregation layer1 (wave per node) + epilogue + fused GEMM2 ------
// each lane holds h1[node][lane]; xt2[node][:] via 64-lane butterfly reduction
__global__ __launch_bounds__(256) void agg1_fused_kernel(
        const int* __restrict__ offsets, const int* __restrict__ cursor,
        const int* __restrict__ sorted_src, const float* __restrict__ dis,
        const unsigned short* __restrict__ xt1b, const float* __restrict__ b1,
        const float* __restrict__ W2, float* __restrict__ xt2) {
    int node = blockIdx.x * 4 + (threadIdx.x >> 6);
    if (node >= NN) return;
    int lane = threadIdx.x & 63;
    int beg = offsets[node], end = cursor[node];
    float dd = dis[node];
    float acc = bf2f(xt1b[(size_t)node * HID + lane]) * (dd * dd);  // self-loop
    for (int base = beg; base < end; base += 64) {
        int m = min(64, end - base);
        int s = 0;
        float nd = 0.f;
        if (lane < m) {
            s = sorted_src[base + lane];   // coalesced batch load of edge list
            nd = dis[s];
        }
        for (int j = 0; j < m; ++j) {
            int sj = __shfl(s, j);
            float nj = __shfl(nd, j);
            acc += bf2f(xt1b[(size_t)sj * HID + lane]) * (nj * dd);  // 128B row
        }
    }
    float h = fmaxf(acc + b1[lane], 0.f);
    float2 w = *(const float2*)(W2 + lane * 2);
    float a0 = h * w.x, a1 = h * w.y;
#pragma unroll
    for (int off = 32; off > 0; off >>= 1) {
        a0 += __shfl_xor(a0, off);
        a1 += __shfl_xor(a1, off);
    }
    if (lane == 0) *(float2*)(xt2 + (size_t)node * 2) = make_float2(a0, a1);
}

// ---------------- pull aggregation layer2 + log_softmax (thread per node) ----
__global__ void agg2_final_kernel(const int* __restrict__ offsets, const int* __restrict__ cursor,
                                  const int* __restrict__ sorted_src,
                                  const float* __restrict__ dis,
                                  const float* __restrict__ xt2,
                                  const float* __restrict__ b2,
                                  float* __restrict__ out) {
    int node = blockIdx.x * 256 + threadIdx.x;
    if (node >= NN) return;
    int beg = offsets[node], end = cursor[node];
    float dd = dis[node];
    float d2 = dd * dd;
    float a0 = xt2[(size_t)node * 2 + 0] * d2;
    float a1 = xt2[(size_t)node * 2 + 1] * d2;
    for (int p = beg; p < end; ++p) {
        int s = sorted_src[p];
        float nrm = dis[s] * dd;
        float2 v = *(const float2*)(xt2 + (size_t)s * 2);
        a0 += v.x * nrm;
        a1 += v.y * nrm;
    }
    float v0 = a0 + b2[0], v1 = a1 + b2[1];
    float m = fmaxf(v0, v1);
    float lse = m + logf(expf(v0 - m) + expf(v1 - m));
    out[(size_t)node * 2 + 0] = v0 - lse;
    out[(size_t)node * 2 + 1] = v1 - lse;
}

extern "C" void kernel_launch(void* const* d_in, const int* in_sizes, int n_in,
                              void* d_out, int out_size, void* d_ws, size_t ws_size,
                              hipStream_t stream) {
    const float* x  = (const float*)d_in[0];
    const int* ei   = (const int*)d_in[1];
    const float* W1 = (const float*)d_in[2];
    const float* b1 = (const float*)d_in[3];
    const float* W2 = (const float*)d_in[4];
    const float* b2 = (const float*)d_in[5];
    const int* src = ei;
    const int* dst = ei + EE;
    float* out = (float*)d_out;

    // workspace layout
    unsigned short* xt1b = (unsigned short*)d_ws;                  // N*64 bf16 = 12.8 MB
    float* dis        = (float*)(xt1b + (size_t)NN * HID);         // N
    int*   offsets    = (int*)(dis + NN);                          // N
    int*   cursor     = offsets + NN;                              // N
    int*   sorted_src = cursor + NN;                               // E
    float* xt2        = (float*)(sorted_src + EE);                 // N*2
    bf16x8* W1p       = (bf16x8*)(xt2 + (size_t)NN * 2);           // 4096*16B
    int*   cnt2d      = (int*)(W1p + 4096);                        // NCH*NB1
    int*   base2d     = cnt2d + NCH * NB1;                         // NCH*NB1
    int*   coarse     = base2d + NCH * NB1;                        // NB1+1
    int2*  pairs      = (int2*)(coarse + NB1 + 1);                 // E*8B

    // CSR build (two-level counting sort by dst; also produces dis/offsets/cursor)
    hist1a_kernel<<<NCH, 256, 0, stream>>>(dst, cnt2d);
    scan1b_kernel<<<1, 256, 0, stream>>>(cnt2d, base2d, coarse);
    scatter1c_kernel<<<NCH, 256, 0, stream>>>(src, dst, base2d, pairs);
    sort2_kernel<<<NB1, 256, 0, stream>>>(pairs, coarse, offsets, cursor, sorted_src, dis);

    // layer 1 (+ fused layer-2 transform)
    packW1_kernel<<<16, 256, 0, stream>>>(W1, W1p);
    gemm1_kernel<<<(NN + 63) / 64, 256, 0, stream>>>(x, W1p, xt1b);
    agg1_fused_kernel<<<(NN + 3) / 4, 256, 0, stream>>>(offsets, cursor, sorted_src,
                                                        dis, xt1b, b1, W2, xt2);

    // layer 2 aggregation + log_softmax
    agg2_final_kernel<<<(NN + 255) / 256, 256, 0, stream>>>(offsets, cursor, sorted_src,
                                                            dis, xt2, b2, out);
}

// Round 7
// 206.406 us; speedup vs baseline: 9.9535x; 1.2151x over previous
//
#include <hip/hip_runtime.h>
#include <hip/hip_bf16.h>

#define NN 100000
#define EE 1600000
#define IN_DIM 512
#define HID 64
#define NB1 391          // coarse buckets (256 nodes each): 391*256 >= NN
#define NCH 98           // chunks
#define CHUNK 16384      // edges per chunk (98*16384 >= EE)

typedef __attribute__((ext_vector_type(8))) short bf16x8;
typedef __attribute__((ext_vector_type(4))) float f32x4;

static __device__ __forceinline__ short f2bf(float f) {
    __hip_bfloat16 h = __float2bfloat16(f);
    return *reinterpret_cast<short*>(&h);
}
static __device__ __forceinline__ float bf2f(unsigned short u) {
    union { unsigned int i; float f; } c; c.i = ((unsigned int)u) << 16;
    return c.f;
}

// ---------------- pass 1a: per-chunk coarse histogram ----------------
__global__ __launch_bounds__(256) void hist1a_kernel(const int* __restrict__ dst,
                                                     int* __restrict__ cnt2d) {
    __shared__ int h[NB1];
    const int t = threadIdx.x;
    for (int i = t; i < NB1; i += 256) h[i] = 0;
    __syncthreads();
    const int base = blockIdx.x * CHUNK;
    for (int i = t; i < CHUNK; i += 256) {
        int e = base + i;
        if (e < EE) atomicAdd(&h[dst[e] >> 8], 1);
    }
    __syncthreads();
    for (int i = t; i < NB1; i += 256) cnt2d[blockIdx.x * NB1 + i] = h[i];
}

// ---------------- pass 1b: 2D scan -> per-(chunk,bucket) bases ----------------
__global__ __launch_bounds__(256) void scan1b_kernel(const int* __restrict__ cnt2d,
                                                     int* __restrict__ base2d,
                                                     int* __restrict__ coarse) {
    __shared__ int tot[NB1];
    __shared__ int off[NB1 + 1];
    const int t = threadIdx.x;
    for (int i = t; i < NB1; i += 256) {
        int s = 0;
        for (int c = 0; c < NCH; ++c) s += cnt2d[c * NB1 + i];
        tot[i] = s;
    }
    __syncthreads();
    if (t == 0) {
        int run = 0;
        for (int b = 0; b < NB1; ++b) { off[b] = run; run += tot[b]; }
        off[NB1] = run;   // == EE
    }
    __syncthreads();
    for (int i = t; i < NB1; i += 256) {
        int run = off[i];
        for (int c = 0; c < NCH; ++c) {
            base2d[c * NB1 + i] = run;
            run += cnt2d[c * NB1 + i];
        }
    }
    for (int i = t; i <= NB1; i += 256) coarse[i] = off[i];
}

// ---------------- pass 1c: bucketed scatter of (src,dst) pairs ----------------
__global__ __launch_bounds__(256) void scatter1c_kernel(const int* __restrict__ src,
                                                        const int* __restrict__ dst,
                                                        const int* __restrict__ base2d,
                                                        int2* __restrict__ pairs) {
    __shared__ int cur[NB1];
    const int t = threadIdx.x;
    for (int i = t; i < NB1; i += 256) cur[i] = base2d[blockIdx.x * NB1 + i];
    __syncthreads();
    const int base = blockIdx.x * CHUNK;
    for (int i = t; i < CHUNK; i += 256) {
        int e = base + i;
        if (e < EE) {
            int s = src[e], d = dst[e];
            int pos = atomicAdd(&cur[d >> 8], 1);
            pairs[pos] = make_int2(s, d);
        }
    }
}

// ---------------- pass 2: per-bucket exact CSR sort + deg/dis/offsets ----------
__global__ __launch_bounds__(256) void sort2_kernel(const int2* __restrict__ pairs,
                                                    const int* __restrict__ coarse,
                                                    int* __restrict__ offsets,
                                                    int* __restrict__ cursor,
                                                    int* __restrict__ sorted_src,
                                                    float* __restrict__ dis) {
    __shared__ int sdeg[256];
    __shared__ int sinc[256];
    __shared__ int scur[256];
    const int b = blockIdx.x;
    const int t = threadIdx.x;
    const int n0 = b << 8;
    const int nn = min(256, NN - n0);
    const int e0 = coarse[b], e1 = coarse[b + 1];

    sdeg[t] = 0;
    __syncthreads();
    for (int e = e0 + t; e < e1; e += 256)
        atomicAdd(&sdeg[pairs[e].y - n0], 1);
    __syncthreads();
    sinc[t] = sdeg[t];
    __syncthreads();
    for (int off = 1; off < 256; off <<= 1) {
        int v = (t >= off) ? sinc[t - off] : 0;
        __syncthreads();
        sinc[t] += v;
        __syncthreads();
    }
    int excl = sinc[t] - sdeg[t];
    scur[t] = excl;
    if (t < nn) {
        offsets[n0 + t] = e0 + excl;
        cursor[n0 + t]  = e0 + excl + sdeg[t];
        dis[n0 + t]     = rsqrtf((float)sdeg[t] + 1.0f);
    }
    __syncthreads();
    for (int e = e0 + t; e < e1; e += 256) {
        int2 p = pairs[e];
        int pos = atomicAdd(&scur[p.y - n0], 1);
        sorted_src[e0 + pos] = p.x;
    }
}

// ---------------- W1 pack: fragment-ordered bf16 ----------------
__global__ void packW1_kernel(const float* __restrict__ W1, bf16x8* __restrict__ W1p) {
    int t = blockIdx.x * 256 + threadIdx.x;   // 0..4095
    if (t >= 4096) return;
    int kstep = t >> 8;
    int kb = (t >> 6) & 3;
    int col = t & 63;
    int kbase = kstep * 32 + kb * 8;
    bf16x8 v;
#pragma unroll
    for (int j = 0; j < 8; ++j) v[j] = f2bf(W1[(size_t)(kbase + j) * HID + col]);
    W1p[t] = v;
}

// ---------------- GEMM1 (MFMA): xt1b = bf16(x @ W1)  [N,512]x[512,64] --------
__global__ __launch_bounds__(256) void gemm1_kernel(const float* __restrict__ x,
                                                    const bf16x8* __restrict__ W1p,
                                                    unsigned short* __restrict__ xt1b) {
    const int wave = threadIdx.x >> 6;
    const int lane = threadIdx.x & 63;
    const int r = lane & 15;        // A row within wave tile / B,C col
    const int kg = lane >> 4;       // k-group
    const int row0 = blockIdx.x * 64 + wave * 16;
    const int rowc = min(row0 + r, NN - 1);
    const float* xr = x + (size_t)rowc * IN_DIM;

    f32x4 acc[4] = {};
#pragma unroll
    for (int ks = 0; ks < 16; ++ks) {
        const int k0 = ks * 32 + kg * 8;
        float4 xa = *(const float4*)(xr + k0);
        float4 xb = *(const float4*)(xr + k0 + 4);
        bf16x8 a;
        a[0] = f2bf(xa.x); a[1] = f2bf(xa.y); a[2] = f2bf(xa.z); a[3] = f2bf(xa.w);
        a[4] = f2bf(xb.x); a[5] = f2bf(xb.y); a[6] = f2bf(xb.z); a[7] = f2bf(xb.w);
        const int bbase = (ks * 4 + kg) * 64;
#pragma unroll
        for (int cb = 0; cb < 4; ++cb) {
            bf16x8 bfr = W1p[bbase + cb * 16 + r];
            acc[cb] = __builtin_amdgcn_mfma_f32_16x16x32_bf16(a, bfr, acc[cb], 0, 0, 0);
        }
    }
    // C/D: col = lane&15 (=r), row = kg*4 + reg
#pragma unroll
    for (int cb = 0; cb < 4; ++cb) {
#pragma unroll
        for (int reg = 0; reg < 4; ++reg) {
            int ro = row0 + kg * 4 + reg;
            if (ro < NN) xt1b[(size_t)ro * HID + cb * 16 + r] =
                (unsigned short)f2bf(acc[cb][reg]);
        }
    }
}

// ------- pull aggregation layer1 (wave/node, 4 edges in flight) + fused GEMM2 --
// lane = (grp=lane>>4)*16 + fl; group g gathers edge jj+g, lane covers feats fl*4..+3
__global__ __launch_bounds__(256) void agg1_fused_kernel(
        const int* __restrict__ offsets, const int* __restrict__ cursor,
        const int* __restrict__ sorted_src, const float* __restrict__ dis,
        const unsigned short* __restrict__ xt1b, const float* __restrict__ b1,
        const float* __restrict__ W2, float* __restrict__ xt2) {
    int node = blockIdx.x * 4 + (threadIdx.x >> 6);
    if (node >= NN) return;
    const int lane = threadIdx.x & 63;
    const int grp = lane >> 4;
    const int fl = lane & 15;
    const int beg = offsets[node], end = cursor[node];
    const float dd = dis[node];
    float acc0 = 0.f, acc1 = 0.f, acc2 = 0.f, acc3 = 0.f;

    for (int base = beg; base < end; base += 64) {
        int m = min(64, end - base);
        int s = 0;
        float nd = 0.f;
        if (lane < m) {
            s = sorted_src[base + lane];   // coalesced batch load
            nd = dis[s];
        }
#pragma unroll 4
        for (int jj = 0; jj < m; jj += 4) {
            int j = jj + grp;                  // <= 63 always
            int sj = __shfl(s, j);
            float nj = __shfl(nd, j);
            float w = (j < m) ? nj : 0.f;
            ushort4 v = *(const ushort4*)(xt1b + (size_t)sj * HID + fl * 4);
            acc0 += bf2f(v.x) * w;
            acc1 += bf2f(v.y) * w;
            acc2 += bf2f(v.z) * w;
            acc3 += bf2f(v.w) * w;
        }
    }
    // sum the 4 edge groups (lanes with equal fl)
    acc0 += __shfl_xor(acc0, 16); acc0 += __shfl_xor(acc0, 32);
    acc1 += __shfl_xor(acc1, 16); acc1 += __shfl_xor(acc1, 32);
    acc2 += __shfl_xor(acc2, 16); acc2 += __shfl_xor(acc2, 32);
    acc3 += __shfl_xor(acc3, 16); acc3 += __shfl_xor(acc3, 32);

    // self-loop + bias + relu (all groups compute identically)
    ushort4 xs = *(const ushort4*)(xt1b + (size_t)node * HID + fl * 4);
    float4 bb = *(const float4*)(b1 + fl * 4);
    float d2 = dd * dd;
    float h0 = fmaxf(acc0 * dd + bf2f(xs.x) * d2 + bb.x, 0.f);
    float h1 = fmaxf(acc1 * dd + bf2f(xs.y) * d2 + bb.y, 0.f);
    float h2 = fmaxf(acc2 * dd + bf2f(xs.z) * d2 + bb.z, 0.f);
    float h3 = fmaxf(acc3 * dd + bf2f(xs.w) * d2 + bb.w, 0.f);

    // fused GEMM2: features f = fl*4+k
    float4 w01 = *(const float4*)(W2 + fl * 8);       // W2[f0][0..1], W2[f1][0..1]
    float4 w23 = *(const float4*)(W2 + fl * 8 + 4);   // W2[f2][0..1], W2[f3][0..1]
    float a0 = h0 * w01.x + h1 * w01.z + h2 * w23.x + h3 * w23.z;
    float a1 = h0 * w01.y + h1 * w01.w + h2 * w23.y + h3 * w23.w;
    a0 += __shfl_xor(a0, 1); a0 += __shfl_xor(a0, 2);
    a0 += __shfl_xor(a0, 4); a0 += __shfl_xor(a0, 8);
    a1 += __shfl_xor(a1, 1); a1 += __shfl_xor(a1, 2);
    a1 += __shfl_xor(a1, 4); a1 += __shfl_xor(a1, 8);
    if (lane == 0) *(float2*)(xt2 + (size_t)node * 2) = make_float2(a0, a1);
}

// ---------------- pull aggregation layer2 + log_softmax (thread per node) ----
__global__ void agg2_final_kernel(const int* __restrict__ offsets, const int* __restrict__ cursor,
                                  const int* __restrict__ sorted_src,
                                  const float* __restrict__ dis,
                                  const float* __restrict__ xt2,
                                  const float* __restrict__ b2,
                                  float* __restrict__ out) {
    int node = blockIdx.x * 256 + threadIdx.x;
    if (node >= NN) return;
    int beg = offsets[node], end = cursor[node];
    float dd = dis[node];
    float d2 = dd * dd;
    float a0 = xt2[(size_t)node * 2 + 0] * d2;
    float a1 = xt2[(size_t)node * 2 + 1] * d2;
    for (int p = beg; p < end; ++p) {
        int s = sorted_src[p];
        float nrm = dis[s] * dd;
        float2 v = *(const float2*)(xt2 + (size_t)s * 2);
        a0 += v.x * nrm;
        a1 += v.y * nrm;
    }
    float v0 = a0 + b2[0], v1 = a1 + b2[1];
    float m = fmaxf(v0, v1);
    float lse = m + logf(expf(v0 - m) + expf(v1 - m));
    out[(size_t)node * 2 + 0] = v0 - lse;
    out[(size_t)node * 2 + 1] = v1 - lse;
}

extern "C" void kernel_launch(void* const* d_in, const int* in_sizes, int n_in,
                              void* d_out, int out_size, void* d_ws, size_t ws_size,
                              hipStream_t stream) {
    const float* x  = (const float*)d_in[0];
    const int* ei   = (const int*)d_in[1];
    const float* W1 = (const float*)d_in[2];
    const float* b1 = (const float*)d_in[3];
    const float* W2 = (const float*)d_in[4];
    const float* b2 = (const float*)d_in[5];
    const int* src = ei;
    const int* dst = ei + EE;
    float* out = (float*)d_out;

    // workspace layout
    unsigned short* xt1b = (unsigned short*)d_ws;                  // N*64 bf16 = 12.8 MB
    float* dis        = (float*)(xt1b + (size_t)NN * HID);         // N
    int*   offsets    = (int*)(dis + NN);                          // N
    int*   cursor     = offsets + NN;                              // N
    int*   sorted_src = cursor + NN;                               // E
    float* xt2        = (float*)(sorted_src + EE);                 // N*2
    bf16x8* W1p       = (bf16x8*)(xt2 + (size_t)NN * 2);           // 4096*16B
    int*   cnt2d      = (int*)(W1p + 4096);                        // NCH*NB1
    int*   base2d     = cnt2d + NCH * NB1;                         // NCH*NB1
    int*   coarse     = base2d + NCH * NB1;                        // NB1+1
    int2*  pairs      = (int2*)(coarse + NB1 + 1);                 // E*8B

    // CSR build (two-level counting sort by dst; also produces dis/offsets/cursor)
    hist1a_kernel<<<NCH, 256, 0, stream>>>(dst, cnt2d);
    scan1b_kernel<<<1, 256, 0, stream>>>(cnt2d, base2d, coarse);
    scatter1c_kernel<<<NCH, 256, 0, stream>>>(src, dst, base2d, pairs);
    sort2_kernel<<<NB1, 256, 0, stream>>>(pairs, coarse, offsets, cursor, sorted_src, dis);

    // layer 1 (+ fused layer-2 transform)
    packW1_kernel<<<16, 256, 0, stream>>>(W1, W1p);
    gemm1_kernel<<<(NN + 63) / 64, 256, 0, stream>>>(x, W1p, xt1b);
    agg1_fused_kernel<<<(NN + 3) / 4, 256, 0, stream>>>(offsets, cursor, sorted_src,
                                                        dis, xt1b, b1, W2, xt2);

    // layer 2 aggregation + log_softmax
    agg2_final_kernel<<<(NN + 255) / 256, 256, 0, stream>>>(offsets, cursor, sorted_src,
                                                            dis, xt2, b2, out);
}

// Round 8
// 182.653 us; speedup vs baseline: 11.2479x; 1.1300x over previous
//
#include <hip/hip_runtime.h>
#include <hip/hip_bf16.h>

#define NN 100000
#define EE 1600000
#define IN_DIM 512
#define HID 64
#define NB1 391          // coarse buckets (256 nodes each): 391*256 >= NN
#define NCH 196          // chunks
#define CHUNK 8192       // edges per chunk (196*8192 >= EE)
#define NGEMM 1563       // (NN+63)/64

typedef __attribute__((ext_vector_type(8))) short bf16x8;
typedef __attribute__((ext_vector_type(4))) float f32x4;

static __device__ __forceinline__ short f2bf(float f) {
    __hip_bfloat16 h = __float2bfloat16(f);
    return *reinterpret_cast<short*>(&h);
}
static __device__ __forceinline__ float bf2f(unsigned short u) {
    union { unsigned int i; float f; } c; c.i = ((unsigned int)u) << 16;
    return c.f;
}

// ---------------- A: W1 pack (blocks 0..15) + per-chunk histogram (rest) -----
__global__ __launch_bounds__(256) void pack_hist_kernel(const float* __restrict__ W1,
                                                        bf16x8* __restrict__ W1p,
                                                        const int* __restrict__ dst,
                                                        int* __restrict__ cnt2d) {
    if (blockIdx.x < 16) {
        // W1p: [kstep 0..15][kb 0..3][col 0..63] of bf16x8 over k
        int t = blockIdx.x * 256 + threadIdx.x;   // 0..4095
        int kstep = t >> 8;
        int kb = (t >> 6) & 3;
        int col = t & 63;
        int kbase = kstep * 32 + kb * 8;
        bf16x8 v;
#pragma unroll
        for (int j = 0; j < 8; ++j) v[j] = f2bf(W1[(size_t)(kbase + j) * HID + col]);
        W1p[t] = v;
    } else {
        __shared__ int h[NB1];
        const int c = blockIdx.x - 16;
        const int t = threadIdx.x;
        for (int i = t; i < NB1; i += 256) h[i] = 0;
        __syncthreads();
        const int base = c * CHUNK;
        for (int i = t; i < CHUNK; i += 256) {
            int e = base + i;
            if (e < EE) atomicAdd(&h[dst[e] >> 8], 1);
        }
        __syncthreads();
        for (int i = t; i < NB1; i += 256) cnt2d[c * NB1 + i] = h[i];
    }
}

// ---------------- B: 2D scan -> per-(chunk,bucket) bases ----------------
__global__ __launch_bounds__(256) void scan1b_kernel(const int* __restrict__ cnt2d,
                                                     int* __restrict__ base2d,
                                                     int* __restrict__ coarse) {
    __shared__ int tot[NB1];
    __shared__ int off[NB1 + 1];
    const int t = threadIdx.x;
    for (int i = t; i < NB1; i += 256) {
        int s = 0;
        for (int c = 0; c < NCH; ++c) s += cnt2d[c * NB1 + i];
        tot[i] = s;
    }
    __syncthreads();
    if (t == 0) {
        int run = 0;
        for (int b = 0; b < NB1; ++b) { off[b] = run; run += tot[b]; }
        off[NB1] = run;   // == EE
    }
    __syncthreads();
    for (int i = t; i < NB1; i += 256) {
        int run = off[i];
        for (int c = 0; c < NCH; ++c) {
            base2d[c * NB1 + i] = run;
            run += cnt2d[c * NB1 + i];
        }
    }
    for (int i = t; i <= NB1; i += 256) coarse[i] = off[i];
}

// ---------------- C: bucketed scatter of packed (src<<8|dstloc) --------------
__global__ __launch_bounds__(256) void scatter1c_kernel(const int* __restrict__ src,
                                                        const int* __restrict__ dst,
                                                        const int* __restrict__ base2d,
                                                        unsigned int* __restrict__ pairs) {
    __shared__ int cur[NB1];
    const int t = threadIdx.x;
    for (int i = t; i < NB1; i += 256) cur[i] = base2d[blockIdx.x * NB1 + i];
    __syncthreads();
    const int base = blockIdx.x * CHUNK;
    for (int i = t; i < CHUNK; i += 256) {
        int e = base + i;
        if (e < EE) {
            int s = src[e], d = dst[e];
            int pos = atomicAdd(&cur[d >> 8], 1);
            pairs[pos] = ((unsigned int)s << 8) | (unsigned int)(d & 255);
        }
    }
}

// ------- D: per-bucket CSR sort (blocks 0..NB1-1) + MFMA GEMM1 (rest) --------
__global__ __launch_bounds__(256) void sort_gemm_kernel(
        const unsigned int* __restrict__ pairs, const int* __restrict__ coarse,
        int* __restrict__ offsets, int* __restrict__ cursor,
        int* __restrict__ sorted_src, float* __restrict__ dis,
        const float* __restrict__ x, const bf16x8* __restrict__ W1p,
        unsigned short* __restrict__ xt1b) {
    if (blockIdx.x < NB1) {
        __shared__ int sdeg[256];
        __shared__ int sinc[256];
        __shared__ int scur[256];
        const int b = blockIdx.x;
        const int t = threadIdx.x;
        const int n0 = b << 8;
        const int nn = min(256, NN - n0);
        const int e0 = coarse[b], e1 = coarse[b + 1];

        sdeg[t] = 0;
        __syncthreads();
        for (int e = e0 + t; e < e1; e += 256)
            atomicAdd(&sdeg[pairs[e] & 255u], 1);
        __syncthreads();
        sinc[t] = sdeg[t];
        __syncthreads();
        for (int off = 1; off < 256; off <<= 1) {
            int v = (t >= off) ? sinc[t - off] : 0;
            __syncthreads();
            sinc[t] += v;
            __syncthreads();
        }
        int excl = sinc[t] - sdeg[t];
        scur[t] = excl;
        if (t < nn) {
            offsets[n0 + t] = e0 + excl;
            cursor[n0 + t]  = e0 + excl + sdeg[t];
            dis[n0 + t]     = rsqrtf((float)sdeg[t] + 1.0f);
        }
        __syncthreads();
        for (int e = e0 + t; e < e1; e += 256) {
            unsigned int p = pairs[e];
            int pos = atomicAdd(&scur[p & 255u], 1);
            sorted_src[e0 + pos] = (int)(p >> 8);
        }
    } else {
        // MFMA GEMM1: wave = 16 rows x 64 cols; block = 4 waves = 64 rows
        const int gb = blockIdx.x - NB1;
        const int wave = threadIdx.x >> 6;
        const int lane = threadIdx.x & 63;
        const int r = lane & 15;        // A row within wave tile / B,C col
        const int kg = lane >> 4;       // k-group
        const int row0 = gb * 64 + wave * 16;
        const int rowc = min(row0 + r, NN - 1);
        const float* xr = x + (size_t)rowc * IN_DIM;

        f32x4 acc[4] = {};
#pragma unroll
        for (int ks = 0; ks < 16; ++ks) {
            const int k0 = ks * 32 + kg * 8;
            float4 xa = *(const float4*)(xr + k0);
            float4 xb = *(const float4*)(xr + k0 + 4);
            bf16x8 a;
            a[0] = f2bf(xa.x); a[1] = f2bf(xa.y); a[2] = f2bf(xa.z); a[3] = f2bf(xa.w);
            a[4] = f2bf(xb.x); a[5] = f2bf(xb.y); a[6] = f2bf(xb.z); a[7] = f2bf(xb.w);
            const int bbase = (ks * 4 + kg) * 64;
#pragma unroll
            for (int cb = 0; cb < 4; ++cb) {
                bf16x8 bfr = W1p[bbase + cb * 16 + r];
                acc[cb] = __builtin_amdgcn_mfma_f32_16x16x32_bf16(a, bfr, acc[cb], 0, 0, 0);
            }
        }
        // C/D: col = lane&15 (=r), row = kg*4 + reg
#pragma unroll
        for (int cb = 0; cb < 4; ++cb) {
#pragma unroll
            for (int reg = 0; reg < 4; ++reg) {
                int ro = row0 + kg * 4 + reg;
                if (ro < NN) xt1b[(size_t)ro * HID + cb * 16 + r] =
                    (unsigned short)f2bf(acc[cb][reg]);
            }
        }
    }
}

// ------- E: pull aggregation layer1 (wave/node, 4 edges in flight) + GEMM2 ----
__global__ __launch_bounds__(256) void agg1_fused_kernel(
        const int* __restrict__ offsets, const int* __restrict__ cursor,
        const int* __restrict__ sorted_src, const float* __restrict__ dis,
        const unsigned short* __restrict__ xt1b, const float* __restrict__ b1,
        const float* __restrict__ W2, float* __restrict__ xt2) {
    int node = blockIdx.x * 4 + (threadIdx.x >> 6);
    if (node >= NN) return;
    const int lane = threadIdx.x & 63;
    const int grp = lane >> 4;
    const int fl = lane & 15;
    const int beg = offsets[node], end = cursor[node];
    const float dd = dis[node];
    float acc0 = 0.f, acc1 = 0.f, acc2 = 0.f, acc3 = 0.f;

    for (int base = beg; base < end; base += 64) {
        int m = min(64, end - base);
        int s = 0;
        float nd = 0.f;
        if (lane < m) {
            s = sorted_src[base + lane];   // coalesced batch load
            nd = dis[s];
        }
#pragma unroll 4
        for (int jj = 0; jj < m; jj += 4) {
            int j = jj + grp;                  // <= 63 always
            int sj = __shfl(s, j);
            float nj = __shfl(nd, j);
            float w = (j < m) ? nj : 0.f;
            ushort4 v = *(const ushort4*)(xt1b + (size_t)sj * HID + fl * 4);
            acc0 += bf2f(v.x) * w;
            acc1 += bf2f(v.y) * w;
            acc2 += bf2f(v.z) * w;
            acc3 += bf2f(v.w) * w;
        }
    }
    // sum the 4 edge groups (lanes with equal fl)
    acc0 += __shfl_xor(acc0, 16); acc0 += __shfl_xor(acc0, 32);
    acc1 += __shfl_xor(acc1, 16); acc1 += __shfl_xor(acc1, 32);
    acc2 += __shfl_xor(acc2, 16); acc2 += __shfl_xor(acc2, 32);
    acc3 += __shfl_xor(acc3, 16); acc3 += __shfl_xor(acc3, 32);

    // self-loop + bias + relu
    ushort4 xs = *(const ushort4*)(xt1b + (size_t)node * HID + fl * 4);
    float4 bb = *(const float4*)(b1 + fl * 4);
    float d2 = dd * dd;
    float h0 = fmaxf(acc0 * dd + bf2f(xs.x) * d2 + bb.x, 0.f);
    float h1 = fmaxf(acc1 * dd + bf2f(xs.y) * d2 + bb.y, 0.f);
    float h2 = fmaxf(acc2 * dd + bf2f(xs.z) * d2 + bb.z, 0.f);
    float h3 = fmaxf(acc3 * dd + bf2f(xs.w) * d2 + bb.w, 0.f);

    // fused GEMM2
    float4 w01 = *(const float4*)(W2 + fl * 8);
    float4 w23 = *(const float4*)(W2 + fl * 8 + 4);
    float a0 = h0 * w01.x + h1 * w01.z + h2 * w23.x + h3 * w23.z;
    float a1 = h0 * w01.y + h1 * w01.w + h2 * w23.y + h3 * w23.w;
    a0 += __shfl_xor(a0, 1); a0 += __shfl_xor(a0, 2);
    a0 += __shfl_xor(a0, 4); a0 += __shfl_xor(a0, 8);
    a1 += __shfl_xor(a1, 1); a1 += __shfl_xor(a1, 2);
    a1 += __shfl_xor(a1, 4); a1 += __shfl_xor(a1, 8);
    if (lane == 0) *(float2*)(xt2 + (size_t)node * 2) = make_float2(a0, a1);
}

// ---------------- F: pull aggregation layer2 + log_softmax -------------------
__global__ void agg2_final_kernel(const int* __restrict__ offsets, const int* __restrict__ cursor,
                                  const int* __restrict__ sorted_src,
                                  const float* __restrict__ dis,
                                  const float* __restrict__ xt2,
                                  const float* __restrict__ b2,
                                  float* __restrict__ out) {
    int node = blockIdx.x * 256 + threadIdx.x;
    if (node >= NN) return;
    int beg = offsets[node], end = cursor[node];
    float dd = dis[node];
    float d2 = dd * dd;
    float a0 = xt2[(size_t)node * 2 + 0] * d2;
    float a1 = xt2[(size_t)node * 2 + 1] * d2;
    for (int p = beg; p < end; ++p) {
        int s = sorted_src[p];
        float nrm = dis[s] * dd;
        float2 v = *(const float2*)(xt2 + (size_t)s * 2);
        a0 += v.x * nrm;
        a1 += v.y * nrm;
    }
    float v0 = a0 + b2[0], v1 = a1 + b2[1];
    float m = fmaxf(v0, v1);
    float lse = m + logf(expf(v0 - m) + expf(v1 - m));
    out[(size_t)node * 2 + 0] = v0 - lse;
    out[(size_t)node * 2 + 1] = v1 - lse;
}

extern "C" void kernel_launch(void* const* d_in, const int* in_sizes, int n_in,
                              void* d_out, int out_size, void* d_ws, size_t ws_size,
                              hipStream_t stream) {
    const float* x  = (const float*)d_in[0];
    const int* ei   = (const int*)d_in[1];
    const float* W1 = (const float*)d_in[2];
    const float* b1 = (const float*)d_in[3];
    const float* W2 = (const float*)d_in[4];
    const float* b2 = (const float*)d_in[5];
    const int* src = ei;
    const int* dst = ei + EE;
    float* out = (float*)d_out;

    // workspace layout
    unsigned short* xt1b = (unsigned short*)d_ws;                  // N*64 bf16 = 12.8 MB
    float* dis        = (float*)(xt1b + (size_t)NN * HID);         // N
    int*   offsets    = (int*)(dis + NN);                          // N
    int*   cursor     = offsets + NN;                              // N
    int*   sorted_src = cursor + NN;                               // E
    float* xt2        = (float*)(sorted_src + EE);                 // N*2
    bf16x8* W1p       = (bf16x8*)(xt2 + (size_t)NN * 2);           // 4096*16B
    int*   cnt2d      = (int*)(W1p + 4096);                        // NCH*NB1
    int*   base2d     = cnt2d + NCH * NB1;                         // NCH*NB1
    int*   coarse     = base2d + NCH * NB1;                        // NB1+1
    unsigned int* pairs = (unsigned int*)(coarse + NB1 + 1);       // E*4B

    // A: W1 pack + coarse histogram
    pack_hist_kernel<<<16 + NCH, 256, 0, stream>>>(W1, W1p, dst, cnt2d);
    // B: 2D scan
    scan1b_kernel<<<1, 256, 0, stream>>>(cnt2d, base2d, coarse);
    // C: bucketed scatter (packed 4B pairs)
    scatter1c_kernel<<<NCH, 256, 0, stream>>>(src, dst, base2d, pairs);
    // D: per-bucket CSR sort  ||  MFMA GEMM1
    sort_gemm_kernel<<<NB1 + NGEMM, 256, 0, stream>>>(pairs, coarse, offsets, cursor,
                                                      sorted_src, dis, x, W1p, xt1b);
    // E: aggregation layer1 + epilogue + fused GEMM2
    agg1_fused_kernel<<<(NN + 3) / 4, 256, 0, stream>>>(offsets, cursor, sorted_src,
                                                        dis, xt1b, b1, W2, xt2);
    // F: aggregation layer2 + log_softmax
    agg2_final_kernel<<<(NN + 255) / 256, 256, 0, stream>>>(offsets, cursor, sorted_src,
                                                            dis, xt2, b2, out);
}